// Round 5
// baseline (735.320 us; speedup 1.0000x reference)
//
#include <hip/hip_runtime.h>
#include <math.h>

#define SCALE 0.17677669529663687f  /* (256/8)^-0.5 */

typedef short short8 __attribute__((ext_vector_type(8)));
typedef float f32x4 __attribute__((ext_vector_type(4)));

// ---------------------------------------------------------------------------
__device__ __forceinline__ int token_row_addr(int m) {
    int b = m / 3136;
    int rem = m - b * 3136;
    int s = rem / 49;
    int tok = rem - s * 49;
    int h = (s >> 3) * 7 + tok / 7;
    int w = (s & 7) * 7 + (tok % 7);
    return (b * 56 + h) * 56 + w;
}

// split fp32 -> bf16 hi (truncate) + bf16 lo (residual, truncate)
__device__ __forceinline__ void split2(float x, unsigned short& h, unsigned short& l) {
    unsigned int u = __float_as_uint(x);
    h = (unsigned short)(u >> 16);
    float hf = __uint_as_float(u & 0xFFFF0000u);
    l = (unsigned short)(__float_as_uint(x - hf) >> 16);
}

__device__ __forceinline__ float b2f(unsigned short u) {
    return __uint_as_float(((unsigned int)u) << 16);
}

// async global->LDS 16B per lane
__device__ __forceinline__ void gload16(const unsigned short* g, unsigned short* l) {
    __builtin_amdgcn_global_load_lds(
        (const __attribute__((address_space(1))) unsigned int*)g,
        (__attribute__((address_space(3))) unsigned int*)l, 16, 0, 0);
}

// ---------------------------------------------------------------------------
// converters
__global__ void k_cvt_x(const float* __restrict__ x, unsigned short* __restrict__ xhi,
                        unsigned short* __restrict__ xlo) {
    int m = blockIdx.x;
    int k = threadIdx.x;
    float v = x[(size_t)token_row_addr(m) * 256 + k];
    unsigned short h, l;
    split2(v, h, l);
    xhi[(size_t)m * 256 + k] = h;
    xlo[(size_t)m * 256 + k] = l;
}

__global__ void k_cvt_w(const float* __restrict__ w, int ncols,
                        unsigned short* __restrict__ whi, unsigned short* __restrict__ wlo) {
    int n = blockIdx.x;
    int k = threadIdx.x;
    float v = w[(size_t)k * ncols + n];
    unsigned short h, l;
    split2(v, h, l);
    whi[(size_t)n * 256 + k] = h;
    wlo[(size_t)n * 256 + k] = l;
}

// ---------------------------------------------------------------------------
// K0a..K0d: fp32 region path (unchanged)
__global__ void k_region_mean(const float* __restrict__ x, float* __restrict__ xr) {
    int blk = blockIdx.x;
    int b = blk >> 6, s = blk & 63;
    int c = threadIdx.x;
    int hy0 = (s >> 3) * 7, wx0 = (s & 7) * 7;
    const float* xb = x + ((size_t)b * 56 * 56) * 256 + c;
    float sum = 0.f;
#pragma unroll 1
    for (int t = 0; t < 49; ++t) {
        int h = hy0 + t / 7, w = wx0 + (t % 7);
        sum += xb[(size_t)(h * 56 + w) * 256];
    }
    xr[(size_t)blk * 256 + c] = sum * (1.0f / 49.0f);
}

__global__ void k_region_qkv(const float* __restrict__ xr, const float* __restrict__ wqkv,
                             const float* __restrict__ bqkv, float* __restrict__ qkvr) {
    __shared__ float xs[256];
    int blk = blockIdx.x;
    int t = threadIdx.x;
    xs[t] = xr[(size_t)blk * 256 + t];
    __syncthreads();
    float a0 = 0.f, a1 = 0.f, a2 = 0.f;
#pragma unroll 4
    for (int k = 0; k < 256; ++k) {
        float xv = xs[k];
        const float* wrow = wqkv + (size_t)k * 768;
        a0 += xv * wrow[t];
        a1 += xv * wrow[t + 256];
        a2 += xv * wrow[t + 512];
    }
    float* o = qkvr + (size_t)blk * 768;
    o[t]       = a0 + bqkv[t];
    o[t + 256] = a1 + bqkv[t + 256];
    o[t + 512] = a2 + bqkv[t + 512];
}

__global__ void k_gating(const float* __restrict__ qkvr, const float* __restrict__ wg1,
                         const float* __restrict__ bg1, const float* __restrict__ wg2,
                         const float* __restrict__ bg2, float* __restrict__ sig) {
    __shared__ float hs[64];
    int blk = blockIdx.x;
    int j = threadIdx.x;
    const float* qr = qkvr + (size_t)blk * 768;
    float acc = bg1[j];
#pragma unroll 4
    for (int k = 0; k < 256; ++k) acc += qr[k] * wg1[(size_t)k * 64 + j];
    hs[j] = fmaxf(acc, 0.f);
    __syncthreads();
    if (j < 2) {
        float gp = bg2[j];
#pragma unroll 1
        for (int m = 0; m < 64; ++m) gp += hs[m] * wg2[m * 2 + j];
        float sp = fmaxf(gp, 0.f) + log1pf(expf(-fabsf(gp)));
        sig[blk * 2 + j] = sp + 0.5f;
    }
}

__global__ void k_topk_gauss(const float* __restrict__ qkvr, const float* __restrict__ sig,
                             int* __restrict__ topk, float* __restrict__ gwt) {
    __shared__ float A[64];
    __shared__ float G[64];
    __shared__ int idxs[4];
    __shared__ float gsum_s;
    int blk = blockIdx.x;
    int b = blk >> 6, s = blk & 63;
    int z = threadIdx.x;
    const float* qr = qkvr + (size_t)blk * 768;
    const float* kr = qkvr + (size_t)(b * 64 + z) * 768 + 256;
    float acc = 0.f;
#pragma unroll 4
    for (int k = 0; k < 256; k += 4) {
        float4 q4 = *(const float4*)(qr + k);
        float4 k4 = *(const float4*)(kr + k);
        acc += q4.x * k4.x + q4.y * k4.y + q4.z * k4.z + q4.w * k4.w;
    }
    A[z] = acc * SCALE;
    float s0 = sig[blk * 2 + 0], s1 = sig[blk * 2 + 1];
    float dx = (float)((z & 7) - (s & 7));
    float dy = (float)((z >> 3) - (s >> 3));
    float t0 = dx / s0, t1 = dy / s1;
    float zz = t0 * t0 + t1 * t1;
    G[z] = expf(-0.5f * zz);
    __syncthreads();
    if (z == 0) {
        float gs = 0.f;
        for (int m = 0; m < 64; ++m) gs += G[m];
        gsum_s = gs + 1e-6f;
        for (int it = 0; it < 4; ++it) {
            int best = 0;
            float bv = A[0];
            for (int m = 1; m < 64; ++m) {
                if (A[m] > bv) { bv = A[m]; best = m; }
            }
            idxs[it] = best;
            A[best] = -3.0e38f;
        }
    }
    __syncthreads();
    if (z < 4) {
        int id = idxs[z];
        topk[blk * 4 + z] = id;
        gwt[blk * 4 + z] = G[id] / gsum_s;
    }
}

// ---------------------------------------------------------------------------
// K1: qkv GEMM, split-bf16 MFMA, 128x128 tile, BK=32. grid (6, 196).
// Epilogue: Q,K -> bf16 hi/lo [token][256]; V -> transposed Vt[win][c][64] hi/lo.
__global__ __launch_bounds__(256) void k_mm_qkv(
    const unsigned short* __restrict__ xhi, const unsigned short* __restrict__ xlo,
    const unsigned short* __restrict__ whi, const unsigned short* __restrict__ wlo,
    const float* __restrict__ bqkv,
    unsigned short* __restrict__ Qh, unsigned short* __restrict__ Ql,
    unsigned short* __restrict__ Kh, unsigned short* __restrict__ Kl,
    unsigned short* __restrict__ Vth, unsigned short* __restrict__ Vtl) {
    __shared__ __align__(16) unsigned short Ah[4096];
    __shared__ __align__(16) unsigned short Al[4096];
    __shared__ __align__(16) unsigned short Bh[4096];
    __shared__ __align__(16) unsigned short Bl[4096];
    int tid = threadIdx.x;
    int ln = tid & 63, wv = tid >> 6;
    int m0 = blockIdx.y * 128, n0 = blockIdx.x * 128;
    int mrow = (wv >> 1) * 64, ncol = (wv & 1) * 64;

    int lrow = ln >> 2, lseg = (ln & 3) * 8;
    const unsigned short* gA0 = xhi + (size_t)(m0 + wv * 32 + lrow) * 256 + lseg;
    const unsigned short* gA1 = gA0 + 16 * 256;
    const unsigned short* gAl0 = xlo + (size_t)(m0 + wv * 32 + lrow) * 256 + lseg;
    const unsigned short* gAl1 = gAl0 + 16 * 256;
    const unsigned short* gB0 = whi + (size_t)(n0 + wv * 32 + lrow) * 256 + lseg;
    const unsigned short* gB1 = gB0 + 16 * 256;
    const unsigned short* gBl0 = wlo + (size_t)(n0 + wv * 32 + lrow) * 256 + lseg;
    const unsigned short* gBl1 = gBl0 + 16 * 256;
    unsigned short* lA0 = &Ah[(wv * 32) * 32];
    unsigned short* lA1 = &Ah[(wv * 32 + 16) * 32];
    unsigned short* lAl0 = &Al[(wv * 32) * 32];
    unsigned short* lAl1 = &Al[(wv * 32 + 16) * 32];
    unsigned short* lB0 = &Bh[(wv * 32) * 32];
    unsigned short* lB1 = &Bh[(wv * 32 + 16) * 32];
    unsigned short* lBl0 = &Bl[(wv * 32) * 32];
    unsigned short* lBl1 = &Bl[(wv * 32 + 16) * 32];

    int fm = ln & 15, fq = (ln >> 4) * 8;
    f32x4 acc[4][4];
#pragma unroll
    for (int i = 0; i < 4; ++i)
#pragma unroll
        for (int j = 0; j < 4; ++j) acc[i][j] = (f32x4){0.f, 0.f, 0.f, 0.f};

#pragma unroll 1
    for (int kc = 0; kc < 8; ++kc) {
        if (kc) __syncthreads();
        gload16(gA0, lA0); gload16(gA1, lA1);
        gload16(gAl0, lAl0); gload16(gAl1, lAl1);
        gload16(gB0, lB0); gload16(gB1, lB1);
        gload16(gBl0, lBl0); gload16(gBl1, lBl1);
        gA0 += 32; gA1 += 32; gAl0 += 32; gAl1 += 32;
        gB0 += 32; gB1 += 32; gBl0 += 32; gBl1 += 32;
        __syncthreads();

        short8 ah[4], bh[4], xx[4];
#pragma unroll
        for (int mi = 0; mi < 4; ++mi)
            ah[mi] = *(const short8*)&Ah[(mrow + mi * 16 + fm) * 32 + fq];
#pragma unroll
        for (int ni = 0; ni < 4; ++ni)
            bh[ni] = *(const short8*)&Bh[(ncol + ni * 16 + fm) * 32 + fq];
#pragma unroll
        for (int mi = 0; mi < 4; ++mi)
#pragma unroll
            for (int ni = 0; ni < 4; ++ni)
                acc[mi][ni] = __builtin_amdgcn_mfma_f32_16x16x32_bf16(ah[mi], bh[ni], acc[mi][ni], 0, 0, 0);
#pragma unroll
        for (int mi = 0; mi < 4; ++mi)
            xx[mi] = *(const short8*)&Al[(mrow + mi * 16 + fm) * 32 + fq];
#pragma unroll
        for (int mi = 0; mi < 4; ++mi)
#pragma unroll
            for (int ni = 0; ni < 4; ++ni)
                acc[mi][ni] = __builtin_amdgcn_mfma_f32_16x16x32_bf16(xx[mi], bh[ni], acc[mi][ni], 0, 0, 0);
#pragma unroll
        for (int ni = 0; ni < 4; ++ni)
            xx[ni] = *(const short8*)&Bl[(ncol + ni * 16 + fm) * 32 + fq];
#pragma unroll
        for (int mi = 0; mi < 4; ++mi)
#pragma unroll
            for (int ni = 0; ni < 4; ++ni)
                acc[mi][ni] = __builtin_amdgcn_mfma_f32_16x16x32_bf16(ah[mi], xx[ni], acc[mi][ni], 0, 0, 0);
    }

    // epilogue: C layout col=lane&15, row=(lane>>4)*4+reg
    int nb = n0 >> 7;  // 0,1->Q  2,3->K  4,5->V
    int qrow = (ln >> 4) * 4;
#pragma unroll
    for (int ni = 0; ni < 4; ++ni) {
        int col = (n0 & 255) + ncol + ni * 16 + fm;  // 0..255 within Q/K/V
        float bias = bqkv[n0 + ncol + ni * 16 + fm];
#pragma unroll
        for (int mi = 0; mi < 4; ++mi) {
#pragma unroll
            for (int r = 0; r < 4; ++r) {
                int m = m0 + mrow + mi * 16 + qrow + r;
                float v = acc[mi][ni][r] + bias;
                unsigned short h, l;
                split2(v, h, l);
                if (nb < 2) {
                    size_t idx = (size_t)m * 256 + col;
                    Qh[idx] = h; Ql[idx] = l;
                } else if (nb < 4) {
                    size_t idx = (size_t)m * 256 + col;
                    Kh[idx] = h; Kl[idx] = l;
                } else {
                    unsigned int wn = (unsigned int)m / 49u;
                    int tok = m - (int)wn * 49;
                    size_t idx = (size_t)wn * 16384 + (size_t)col * 64 + tok;
                    Vth[idx] = h; Vtl[idx] = l;
                }
            }
        }
    }
}

// ---------------------------------------------------------------------------
// K2a: per-window QK^T via split-bf16 MFMA (direct global frag loads, no staging)
// + LDS softmax + P write (gwt folded) as bf16 hi/lo Pt[win][w(64)][j(256)].
// grid 512, block 256; wave wv = region chunk wv.
__global__ __launch_bounds__(256) void k_attn_logits_mfma(
    const unsigned short* __restrict__ Qh, const unsigned short* __restrict__ Ql,
    const unsigned short* __restrict__ Kh, const unsigned short* __restrict__ Kl,
    const int* __restrict__ topk, const float* __restrict__ gwt,
    unsigned short* __restrict__ Pth, unsigned short* __restrict__ Ptl) {
    __shared__ float Ls[49][209];
    __shared__ float red[49][4];
    __shared__ float rowm[49];
    __shared__ float rinv49[49];
    __shared__ float gws[4];
    int win = blockIdx.x;
    int b = win >> 6;
    int tid = threadIdx.x;
    int ln = tid & 63, wv = tid >> 6;
    int fm = ln & 15, fq = (ln >> 4) * 8;

    // init col pads to -3e38 (tok 49..51 region-relative)
    for (int idx = tid; idx < 49 * 12; idx += 256) {
        int w = idx / 12, t = idx - w * 12;
        int r = t >> 2, p = t & 3;  // r 0..2? need r 0..3,p 0..2 -> use /3
        (void)r; (void)p;
    }
    // (correct pad init below)
    for (int idx = tid; idx < 588; idx += 256) {  // 49*12
        int w = idx / 12, t = idx - w * 12;
        int r = t / 3, p = t - r * 3;
        Ls[w][r * 52 + 49 + p] = -3.0e38f;
    }
    if (tid < 4) gws[tid] = gwt[win * 4 + tid];

    int reg = topk[win * 4 + wv];
    float sg = SCALE * gwt[win * 4 + wv];
    const size_t qbase = (size_t)win * 49 * 256;
    const size_t kbase = (size_t)(b * 64 + reg) * 49 * 256;

    f32x4 acc[4][4];
#pragma unroll
    for (int i = 0; i < 4; ++i)
#pragma unroll
        for (int j = 0; j < 4; ++j) acc[i][j] = (f32x4){0.f, 0.f, 0.f, 0.f};

#pragma unroll 1
    for (int kc = 0; kc < 256; kc += 32) {
        short8 ah[4], al[4], bh[4], bl[4];
#pragma unroll
        for (int mi = 0; mi < 4; ++mi) {
            size_t o = qbase + (size_t)(mi * 16 + fm) * 256 + kc + fq;
            ah[mi] = *(const short8*)&Qh[o];
            al[mi] = *(const short8*)&Ql[o];
        }
#pragma unroll
        for (int ni = 0; ni < 4; ++ni) {
            size_t o = kbase + (size_t)(ni * 16 + fm) * 256 + kc + fq;
            bh[ni] = *(const short8*)&Kh[o];
            bl[ni] = *(const short8*)&Kl[o];
        }
#pragma unroll
        for (int mi = 0; mi < 4; ++mi)
#pragma unroll
            for (int ni = 0; ni < 4; ++ni) {
                acc[mi][ni] = __builtin_amdgcn_mfma_f32_16x16x32_bf16(ah[mi], bh[ni], acc[mi][ni], 0, 0, 0);
                acc[mi][ni] = __builtin_amdgcn_mfma_f32_16x16x32_bf16(al[mi], bh[ni], acc[mi][ni], 0, 0, 0);
                acc[mi][ni] = __builtin_amdgcn_mfma_f32_16x16x32_bf16(ah[mi], bl[ni], acc[mi][ni], 0, 0, 0);
            }
    }

    // store logits to Ls (predicated to valid w/tok)
    int qrow = (ln >> 4) * 4;
#pragma unroll
    for (int mi = 0; mi < 4; ++mi) {
#pragma unroll
        for (int r = 0; r < 4; ++r) {
            int w = mi * 16 + qrow + r;
            if (w < 49) {
#pragma unroll
                for (int ni = 0; ni < 4; ++ni) {
                    int tok = ni * 16 + fm;
                    if (tok < 49) Ls[w][wv * 52 + tok] = acc[mi][ni][r] * sg;
                }
            }
        }
    }
    __syncthreads();

    // softmax over 208 cols, 4 threads/row
    int sw = tid >> 2, sp = tid & 3;
    if (tid < 196) {
        float m = -3.0e38f;
        for (int j = sp; j < 208; j += 4) m = fmaxf(m, Ls[sw][j]);
        red[sw][sp] = m;
    }
    __syncthreads();
    if (tid < 49)
        rowm[tid] = fmaxf(fmaxf(red[tid][0], red[tid][1]), fmaxf(red[tid][2], red[tid][3]));
    __syncthreads();
    if (tid < 196) {
        float m = rowm[sw], s = 0.f;
        for (int j = sp; j < 208; j += 4) {
            float e = expf(Ls[sw][j] - m);
            Ls[sw][j] = e;
            s += e;
        }
        red[sw][sp] = s;
    }
    __syncthreads();
    if (tid < 49)
        rinv49[tid] = 1.0f / (red[tid][0] + red[tid][1] + red[tid][2] + red[tid][3]);
    __syncthreads();

    // P write: Pt[win][w][r*64+tok] = (w<49 && tok<49) ? Ls*rinv*gwt : 0
    {
        int w = tid >> 2, r = tid & 3;
        float rv = (w < 49) ? rinv49[w] * gws[r] : 0.f;
        size_t base = (size_t)win * 16384 + (size_t)w * 256 + r * 64;
#pragma unroll 1
        for (int tok = 0; tok < 64; ++tok) {
            float v = 0.f;
            if (w < 49 && tok < 49) v = Ls[w][r * 52 + tok] * rv;
            unsigned short h, l;
            split2(v, h, l);
            Pth[base + tok] = h;
            Ptl[base + tok] = l;
        }
    }
}

// ---------------------------------------------------------------------------
// K2b: PV via split-bf16 MFMA (direct global frag loads) + fused dwconv.
// out[w][c] = sum_j P[w][j] * Vt[j][c]; writes ATT bf16 hi/lo. grid 512.
__global__ __launch_bounds__(256) void k_attn_pv_mfma(
    const unsigned short* __restrict__ Pth, const unsigned short* __restrict__ Ptl,
    const unsigned short* __restrict__ Vth, const unsigned short* __restrict__ Vtl,
    const int* __restrict__ topk, const float* __restrict__ dwk,
    const float* __restrict__ dwb, unsigned short* __restrict__ atth,
    unsigned short* __restrict__ attl) {
    int win = blockIdx.x;
    int b = win >> 6;
    int tid = threadIdx.x;
    int ln = tid & 63, wv = tid >> 6;
    int fm = ln & 15, fq = (ln >> 4) * 8;
    int ncol = wv * 64;
    size_t pbase = (size_t)win * 16384;

    f32x4 acc[4][4];
#pragma unroll
    for (int i = 0; i < 4; ++i)
#pragma unroll
        for (int j = 0; j < 4; ++j) acc[i][j] = (f32x4){0.f, 0.f, 0.f, 0.f};

#pragma unroll 1
    for (int r = 0; r < 4; ++r) {
        int reg = topk[win * 4 + r];
        size_t vbase = (size_t)(b * 64 + reg) * 16384;
#pragma unroll
        for (int half = 0; half < 2; ++half) {
            int kc = r * 64 + half * 32;
            int vt = half * 32;
            short8 ah[4], al[4], bh[4], bl[4];
#pragma unroll
            for (int mi = 0; mi < 4; ++mi) {
                size_t o = pbase + (size_t)(mi * 16 + fm) * 256 + kc + fq;
                ah[mi] = *(const short8*)&Pth[o];
                al[mi] = *(const short8*)&Ptl[o];
            }
#pragma unroll
            for (int ni = 0; ni < 4; ++ni) {
                size_t o = vbase + (size_t)(ncol + ni * 16 + fm) * 64 + vt + fq;
                bh[ni] = *(const short8*)&Vth[o];
                bl[ni] = *(const short8*)&Vtl[o];
            }
#pragma unroll
            for (int mi = 0; mi < 4; ++mi)
#pragma unroll
                for (int ni = 0; ni < 4; ++ni) {
                    acc[mi][ni] = __builtin_amdgcn_mfma_f32_16x16x32_bf16(ah[mi], bh[ni], acc[mi][ni], 0, 0, 0);
                    acc[mi][ni] = __builtin_amdgcn_mfma_f32_16x16x32_bf16(al[mi], bh[ni], acc[mi][ni], 0, 0, 0);
                    acc[mi][ni] = __builtin_amdgcn_mfma_f32_16x16x32_bf16(ah[mi], bl[ni], acc[mi][ni], 0, 0, 0);
                }
        }
    }

    // epilogue: dwconv on own-window V (from Vt, contiguous in tok) + store
    int qrow = (ln >> 4) * 4;
    size_t vown = (size_t)win * 16384;
#pragma unroll 1
    for (int ni = 0; ni < 4; ++ni) {
        int c = ncol + ni * 16 + fm;
        float dk[9];
#pragma unroll
        for (int t = 0; t < 9; ++t) dk[t] = dwk[(size_t)t * 256 + c];
        float db = dwb[c];
        const unsigned short* vh = Vth + vown + (size_t)c * 64;
        const unsigned short* vl = Vtl + vown + (size_t)c * 64;
#pragma unroll
        for (int mi = 0; mi < 4; ++mi) {
#pragma unroll
            for (int rr = 0; rr < 4; ++rr) {
                int w = mi * 16 + qrow + rr;
                if (w < 49) {
                    int py = w / 7, px = w - py * 7;
                    float vd = db;
#pragma unroll
                    for (int dy = 0; dy < 3; ++dy) {
                        int yy = py + dy - 1;
                        if (yy < 0 || yy > 6) continue;
#pragma unroll
                        for (int dx = 0; dx < 3; ++dx) {
                            int xx = px + dx - 1;
                            if (xx < 0 || xx > 6) continue;
                            int nt = yy * 7 + xx;
                            float v = b2f(vh[nt]) + b2f(vl[nt]);
                            vd += v * dk[dy * 3 + dx];
                        }
                    }
                    float o = acc[mi][ni][rr] + vd;
                    unsigned short h, l;
                    split2(o, h, l);
                    size_t idx = ((size_t)win * 49 + w) * 256 + c;
                    atth[idx] = h;
                    attl[idx] = l;
                }
            }
        }
    }
}

// ---------------------------------------------------------------------------
// K3: proj GEMM, split-bf16 MFMA. M=25088, K=256, N=256. grid (2, 196).
__global__ __launch_bounds__(256) void k_mm_proj(
    const unsigned short* __restrict__ ahi, const unsigned short* __restrict__ alo,
    const unsigned short* __restrict__ whi, const unsigned short* __restrict__ wlo,
    const float* __restrict__ bp, float* __restrict__ out) {
    __shared__ __align__(16) unsigned short Ah[4096];
    __shared__ __align__(16) unsigned short Al[4096];
    __shared__ __align__(16) unsigned short Bh[4096];
    __shared__ __align__(16) unsigned short Bl[4096];
    int tid = threadIdx.x;
    int ln = tid & 63, wv = tid >> 6;
    int m0 = blockIdx.y * 128, n0 = blockIdx.x * 128;
    int mrow = (wv >> 1) * 64, ncol = (wv & 1) * 64;

    int lrow = ln >> 2, lseg = (ln & 3) * 8;
    const unsigned short* gA0 = ahi + (size_t)(m0 + wv * 32 + lrow) * 256 + lseg;
    const unsigned short* gA1 = gA0 + 16 * 256;
    const unsigned short* gAl0 = alo + (size_t)(m0 + wv * 32 + lrow) * 256 + lseg;
    const unsigned short* gAl1 = gAl0 + 16 * 256;
    const unsigned short* gB0 = whi + (size_t)(n0 + wv * 32 + lrow) * 256 + lseg;
    const unsigned short* gB1 = gB0 + 16 * 256;
    const unsigned short* gBl0 = wlo + (size_t)(n0 + wv * 32 + lrow) * 256 + lseg;
    const unsigned short* gBl1 = gBl0 + 16 * 256;
    unsigned short* lA0 = &Ah[(wv * 32) * 32];
    unsigned short* lA1 = &Ah[(wv * 32 + 16) * 32];
    unsigned short* lAl0 = &Al[(wv * 32) * 32];
    unsigned short* lAl1 = &Al[(wv * 32 + 16) * 32];
    unsigned short* lB0 = &Bh[(wv * 32) * 32];
    unsigned short* lB1 = &Bh[(wv * 32 + 16) * 32];
    unsigned short* lBl0 = &Bl[(wv * 32) * 32];
    unsigned short* lBl1 = &Bl[(wv * 32 + 16) * 32];

    int fm = ln & 15, fq = (ln >> 4) * 8;
    f32x4 acc[4][4];
#pragma unroll
    for (int i = 0; i < 4; ++i)
#pragma unroll
        for (int j = 0; j < 4; ++j) acc[i][j] = (f32x4){0.f, 0.f, 0.f, 0.f};

#pragma unroll 1
    for (int kc = 0; kc < 8; ++kc) {
        if (kc) __syncthreads();
        gload16(gA0, lA0); gload16(gA1, lA1);
        gload16(gAl0, lAl0); gload16(gAl1, lAl1);
        gload16(gB0, lB0); gload16(gB1, lB1);
        gload16(gBl0, lBl0); gload16(gBl1, lBl1);
        gA0 += 32; gA1 += 32; gAl0 += 32; gAl1 += 32;
        gB0 += 32; gB1 += 32; gBl0 += 32; gBl1 += 32;
        __syncthreads();

        short8 ah[4], bh[4], xx[4];
#pragma unroll
        for (int mi = 0; mi < 4; ++mi)
            ah[mi] = *(const short8*)&Ah[(mrow + mi * 16 + fm) * 32 + fq];
#pragma unroll
        for (int ni = 0; ni < 4; ++ni)
            bh[ni] = *(const short8*)&Bh[(ncol + ni * 16 + fm) * 32 + fq];
#pragma unroll
        for (int mi = 0; mi < 4; ++mi)
#pragma unroll
            for (int ni = 0; ni < 4; ++ni)
                acc[mi][ni] = __builtin_amdgcn_mfma_f32_16x16x32_bf16(ah[mi], bh[ni], acc[mi][ni], 0, 0, 0);
#pragma unroll
        for (int mi = 0; mi < 4; ++mi)
            xx[mi] = *(const short8*)&Al[(mrow + mi * 16 + fm) * 32 + fq];
#pragma unroll
        for (int mi = 0; mi < 4; ++mi)
#pragma unroll
            for (int ni = 0; ni < 4; ++ni)
                acc[mi][ni] = __builtin_amdgcn_mfma_f32_16x16x32_bf16(xx[mi], bh[ni], acc[mi][ni], 0, 0, 0);
#pragma unroll
        for (int ni = 0; ni < 4; ++ni)
            xx[ni] = *(const short8*)&Bl[(ncol + ni * 16 + fm) * 32 + fq];
#pragma unroll
        for (int mi = 0; mi < 4; ++mi)
#pragma unroll
            for (int ni = 0; ni < 4; ++ni)
                acc[mi][ni] = __builtin_amdgcn_mfma_f32_16x16x32_bf16(ah[mi], xx[ni], acc[mi][ni], 0, 0, 0);
    }

    int qrow = (ln >> 4) * 4;
#pragma unroll
    for (int mi = 0; mi < 4; ++mi) {
#pragma unroll
        for (int r = 0; r < 4; ++r) {
            int m = m0 + mrow + mi * 16 + qrow + r;
            size_t orow = (size_t)token_row_addr(m);
#pragma unroll
            for (int ni = 0; ni < 4; ++ni) {
                int col = n0 + ncol + ni * 16 + fm;
                out[orow * 256 + col] = acc[mi][ni][r] + bp[col];
            }
        }
    }
}

// ---------------------------------------------------------------------------
extern "C" void kernel_launch(void* const* d_in, const int* in_sizes, int n_in,
                              void* d_out, int out_size, void* d_ws, size_t ws_size,
                              hipStream_t stream) {
    const float* x    = (const float*)d_in[0];
    const float* wqkv = (const float*)d_in[1];
    const float* bqkv = (const float*)d_in[2];
    const float* wg1  = (const float*)d_in[3];
    const float* bg1  = (const float*)d_in[4];
    const float* wg2  = (const float*)d_in[5];
    const float* bg2  = (const float*)d_in[6];
    const float* dwk  = (const float*)d_in[7];
    const float* dwb  = (const float*)d_in[8];
    const float* wp   = (const float*)d_in[9];
    const float* bp   = (const float*)d_in[10];
    float* out = (float*)d_out;

    const size_t NTOT = (size_t)25088 * 256;   // 6,422,528
    const size_t VTSZ = (size_t)512 * 256 * 64;  // 8,388,608
    unsigned short* Qh  = (unsigned short*)d_ws;
    unsigned short* Ql  = Qh + NTOT;
    unsigned short* Kh  = Ql + NTOT;
    unsigned short* Kl  = Kh + NTOT;
    unsigned short* Vth = Kl + NTOT;
    unsigned short* Vtl = Vth + VTSZ;
    unsigned short* Pth = Vtl + VTSZ;
    unsigned short* Ptl = Pth + VTSZ;
    unsigned short* XH  = Ptl + VTSZ;   // x bf16 windowed; reused as ATT hi
    unsigned short* XL  = XH + NTOT;    // reused as ATT lo
    unsigned short* WQH = XL + NTOT;
    unsigned short* WQL = WQH + 768 * 256;
    unsigned short* WPH = WQL + 768 * 256;
    unsigned short* WPL = WPH + 256 * 256;
    float* XR   = (float*)(WPL + 256 * 256);
    float* QKVR = XR + 512 * 256;
    float* SIG  = QKVR + 512 * 768;
    float* GWT  = SIG + 1024;
    int*   TOPK = (int*)(GWT + 2048);

    hipLaunchKernelGGL(k_cvt_x, dim3(25088), dim3(256), 0, stream, x, XH, XL);
    hipLaunchKernelGGL(k_cvt_w, dim3(768), dim3(256), 0, stream, wqkv, 768, WQH, WQL);
    hipLaunchKernelGGL(k_cvt_w, dim3(256), dim3(256), 0, stream, wp, 256, WPH, WPL);
    hipLaunchKernelGGL(k_region_mean, dim3(512), dim3(256), 0, stream, x, XR);
    hipLaunchKernelGGL(k_region_qkv, dim3(512), dim3(256), 0, stream, XR, wqkv, bqkv, QKVR);
    hipLaunchKernelGGL(k_gating, dim3(512), dim3(64), 0, stream, QKVR, wg1, bg1, wg2, bg2, SIG);
    hipLaunchKernelGGL(k_topk_gauss, dim3(512), dim3(64), 0, stream, QKVR, SIG, TOPK, GWT);
    hipLaunchKernelGGL(k_mm_qkv, dim3(6, 196), dim3(256), 0, stream,
                       XH, XL, WQH, WQL, bqkv, Qh, Ql, Kh, Kl, Vth, Vtl);
    hipLaunchKernelGGL(k_attn_logits_mfma, dim3(512), dim3(256), 0, stream,
                       Qh, Ql, Kh, Kl, TOPK, GWT, Pth, Ptl);
    hipLaunchKernelGGL(k_attn_pv_mfma, dim3(512), dim3(256), 0, stream,
                       Pth, Ptl, Vth, Vtl, TOPK, dwk, dwb, XH, XL);
    hipLaunchKernelGGL(k_mm_proj, dim3(2, 196), dim3(256), 0, stream,
                       XH, XL, WPH, WPL, bp, out);
}

// Round 6
// 516.753 us; speedup vs baseline: 1.4230x; 1.4230x over previous
//
#include <hip/hip_runtime.h>
#include <math.h>

#define SCALE 0.17677669529663687f  /* (256/8)^-0.5 */

typedef short short8 __attribute__((ext_vector_type(8)));
typedef float f32x4 __attribute__((ext_vector_type(4)));

// ---------------------------------------------------------------------------
__device__ __forceinline__ int token_row_addr(int m) {
    int b = m / 3136;
    int rem = m - b * 3136;
    int s = rem / 49;
    int tok = rem - s * 49;
    int h = (s >> 3) * 7 + tok / 7;
    int w = (s & 7) * 7 + (tok % 7);
    return (b * 56 + h) * 56 + w;
}

// split fp32 -> bf16 hi (truncate) + bf16 lo (residual, truncate)
__device__ __forceinline__ void split2(float x, unsigned short& h, unsigned short& l) {
    unsigned int u = __float_as_uint(x);
    h = (unsigned short)(u >> 16);
    float hf = __uint_as_float(u & 0xFFFF0000u);
    l = (unsigned short)(__float_as_uint(x - hf) >> 16);
}

__device__ __forceinline__ float b2f(unsigned short u) {
    return __uint_as_float(((unsigned int)u) << 16);
}

// async global->LDS 16B per lane
__device__ __forceinline__ void gload16(const unsigned short* g, unsigned short* l) {
    __builtin_amdgcn_global_load_lds(
        (const __attribute__((address_space(1))) unsigned int*)g,
        (__attribute__((address_space(3))) unsigned int*)l, 16, 0, 0);
}

// ---------------------------------------------------------------------------
// converters
__global__ void k_cvt_x(const float* __restrict__ x, unsigned short* __restrict__ xhi,
                        unsigned short* __restrict__ xlo) {
    int m = blockIdx.x;
    int k = threadIdx.x;
    float v = x[(size_t)token_row_addr(m) * 256 + k];
    unsigned short h, l;
    split2(v, h, l);
    xhi[(size_t)m * 256 + k] = h;
    xlo[(size_t)m * 256 + k] = l;
}

__global__ void k_cvt_w(const float* __restrict__ w, int ncols,
                        unsigned short* __restrict__ whi, unsigned short* __restrict__ wlo) {
    int n = blockIdx.x;
    int k = threadIdx.x;
    float v = w[(size_t)k * ncols + n];
    unsigned short h, l;
    split2(v, h, l);
    whi[(size_t)n * 256 + k] = h;
    wlo[(size_t)n * 256 + k] = l;
}

// ---------------------------------------------------------------------------
// K0a..K0d: fp32 region path (unchanged)
__global__ void k_region_mean(const float* __restrict__ x, float* __restrict__ xr) {
    int blk = blockIdx.x;
    int b = blk >> 6, s = blk & 63;
    int c = threadIdx.x;
    int hy0 = (s >> 3) * 7, wx0 = (s & 7) * 7;
    const float* xb = x + ((size_t)b * 56 * 56) * 256 + c;
    float sum = 0.f;
#pragma unroll 1
    for (int t = 0; t < 49; ++t) {
        int h = hy0 + t / 7, w = wx0 + (t % 7);
        sum += xb[(size_t)(h * 56 + w) * 256];
    }
    xr[(size_t)blk * 256 + c] = sum * (1.0f / 49.0f);
}

__global__ void k_region_qkv(const float* __restrict__ xr, const float* __restrict__ wqkv,
                             const float* __restrict__ bqkv, float* __restrict__ qkvr) {
    __shared__ float xs[256];
    int blk = blockIdx.x;
    int t = threadIdx.x;
    xs[t] = xr[(size_t)blk * 256 + t];
    __syncthreads();
    float a0 = 0.f, a1 = 0.f, a2 = 0.f;
#pragma unroll 4
    for (int k = 0; k < 256; ++k) {
        float xv = xs[k];
        const float* wrow = wqkv + (size_t)k * 768;
        a0 += xv * wrow[t];
        a1 += xv * wrow[t + 256];
        a2 += xv * wrow[t + 512];
    }
    float* o = qkvr + (size_t)blk * 768;
    o[t]       = a0 + bqkv[t];
    o[t + 256] = a1 + bqkv[t + 256];
    o[t + 512] = a2 + bqkv[t + 512];
}

__global__ void k_gating(const float* __restrict__ qkvr, const float* __restrict__ wg1,
                         const float* __restrict__ bg1, const float* __restrict__ wg2,
                         const float* __restrict__ bg2, float* __restrict__ sig) {
    __shared__ float hs[64];
    int blk = blockIdx.x;
    int j = threadIdx.x;
    const float* qr = qkvr + (size_t)blk * 768;
    float acc = bg1[j];
#pragma unroll 4
    for (int k = 0; k < 256; ++k) acc += qr[k] * wg1[(size_t)k * 64 + j];
    hs[j] = fmaxf(acc, 0.f);
    __syncthreads();
    if (j < 2) {
        float gp = bg2[j];
#pragma unroll 1
        for (int m = 0; m < 64; ++m) gp += hs[m] * wg2[m * 2 + j];
        float sp = fmaxf(gp, 0.f) + log1pf(expf(-fabsf(gp)));
        sig[blk * 2 + j] = sp + 0.5f;
    }
}

__global__ void k_topk_gauss(const float* __restrict__ qkvr, const float* __restrict__ sig,
                             int* __restrict__ topk, float* __restrict__ gwt) {
    __shared__ float A[64];
    __shared__ float G[64];
    __shared__ int idxs[4];
    __shared__ float gsum_s;
    int blk = blockIdx.x;
    int b = blk >> 6, s = blk & 63;
    int z = threadIdx.x;
    const float* qr = qkvr + (size_t)blk * 768;
    const float* kr = qkvr + (size_t)(b * 64 + z) * 768 + 256;
    float acc = 0.f;
#pragma unroll 4
    for (int k = 0; k < 256; k += 4) {
        float4 q4 = *(const float4*)(qr + k);
        float4 k4 = *(const float4*)(kr + k);
        acc += q4.x * k4.x + q4.y * k4.y + q4.z * k4.z + q4.w * k4.w;
    }
    A[z] = acc * SCALE;
    float s0 = sig[blk * 2 + 0], s1 = sig[blk * 2 + 1];
    float dx = (float)((z & 7) - (s & 7));
    float dy = (float)((z >> 3) - (s >> 3));
    float t0 = dx / s0, t1 = dy / s1;
    float zz = t0 * t0 + t1 * t1;
    G[z] = expf(-0.5f * zz);
    __syncthreads();
    if (z == 0) {
        float gs = 0.f;
        for (int m = 0; m < 64; ++m) gs += G[m];
        gsum_s = gs + 1e-6f;
        for (int it = 0; it < 4; ++it) {
            int best = 0;
            float bv = A[0];
            for (int m = 1; m < 64; ++m) {
                if (A[m] > bv) { bv = A[m]; best = m; }
            }
            idxs[it] = best;
            A[best] = -3.0e38f;
        }
    }
    __syncthreads();
    if (z < 4) {
        int id = idxs[z];
        topk[blk * 4 + z] = id;
        gwt[blk * 4 + z] = G[id] / gsum_s;
    }
}

// ---------------------------------------------------------------------------
// K1: qkv GEMM, split-bf16 MFMA, 128x128 tile, BK=32. grid (6, 196).
// Epilogue: Q,K,V -> bf16 hi/lo [token][256].
__global__ __launch_bounds__(256) void k_mm_qkv(
    const unsigned short* __restrict__ xhi, const unsigned short* __restrict__ xlo,
    const unsigned short* __restrict__ whi, const unsigned short* __restrict__ wlo,
    const float* __restrict__ bqkv,
    unsigned short* __restrict__ Qh, unsigned short* __restrict__ Ql,
    unsigned short* __restrict__ Kh, unsigned short* __restrict__ Kl,
    unsigned short* __restrict__ Vh, unsigned short* __restrict__ Vl) {
    __shared__ __align__(16) unsigned short Ah[4096];
    __shared__ __align__(16) unsigned short Al[4096];
    __shared__ __align__(16) unsigned short Bh[4096];
    __shared__ __align__(16) unsigned short Bl[4096];
    int tid = threadIdx.x;
    int ln = tid & 63, wv = tid >> 6;
    int m0 = blockIdx.y * 128, n0 = blockIdx.x * 128;
    int mrow = (wv >> 1) * 64, ncol = (wv & 1) * 64;

    int lrow = ln >> 2, lseg = (ln & 3) * 8;
    const unsigned short* gA0 = xhi + (size_t)(m0 + wv * 32 + lrow) * 256 + lseg;
    const unsigned short* gA1 = gA0 + 16 * 256;
    const unsigned short* gAl0 = xlo + (size_t)(m0 + wv * 32 + lrow) * 256 + lseg;
    const unsigned short* gAl1 = gAl0 + 16 * 256;
    const unsigned short* gB0 = whi + (size_t)(n0 + wv * 32 + lrow) * 256 + lseg;
    const unsigned short* gB1 = gB0 + 16 * 256;
    const unsigned short* gBl0 = wlo + (size_t)(n0 + wv * 32 + lrow) * 256 + lseg;
    const unsigned short* gBl1 = gBl0 + 16 * 256;
    unsigned short* lA0 = &Ah[(wv * 32) * 32];
    unsigned short* lA1 = &Ah[(wv * 32 + 16) * 32];
    unsigned short* lAl0 = &Al[(wv * 32) * 32];
    unsigned short* lAl1 = &Al[(wv * 32 + 16) * 32];
    unsigned short* lB0 = &Bh[(wv * 32) * 32];
    unsigned short* lB1 = &Bh[(wv * 32 + 16) * 32];
    unsigned short* lBl0 = &Bl[(wv * 32) * 32];
    unsigned short* lBl1 = &Bl[(wv * 32 + 16) * 32];

    int fm = ln & 15, fq = (ln >> 4) * 8;
    f32x4 acc[4][4];
#pragma unroll
    for (int i = 0; i < 4; ++i)
#pragma unroll
        for (int j = 0; j < 4; ++j) acc[i][j] = (f32x4){0.f, 0.f, 0.f, 0.f};

#pragma unroll 1
    for (int kc = 0; kc < 8; ++kc) {
        if (kc) __syncthreads();
        gload16(gA0, lA0); gload16(gA1, lA1);
        gload16(gAl0, lAl0); gload16(gAl1, lAl1);
        gload16(gB0, lB0); gload16(gB1, lB1);
        gload16(gBl0, lBl0); gload16(gBl1, lBl1);
        gA0 += 32; gA1 += 32; gAl0 += 32; gAl1 += 32;
        gB0 += 32; gB1 += 32; gBl0 += 32; gBl1 += 32;
        __syncthreads();

        short8 ah[4], bh[4], xx[4];
#pragma unroll
        for (int mi = 0; mi < 4; ++mi)
            ah[mi] = *(const short8*)&Ah[(mrow + mi * 16 + fm) * 32 + fq];
#pragma unroll
        for (int ni = 0; ni < 4; ++ni)
            bh[ni] = *(const short8*)&Bh[(ncol + ni * 16 + fm) * 32 + fq];
#pragma unroll
        for (int mi = 0; mi < 4; ++mi)
#pragma unroll
            for (int ni = 0; ni < 4; ++ni)
                acc[mi][ni] = __builtin_amdgcn_mfma_f32_16x16x32_bf16(ah[mi], bh[ni], acc[mi][ni], 0, 0, 0);
#pragma unroll
        for (int mi = 0; mi < 4; ++mi)
            xx[mi] = *(const short8*)&Al[(mrow + mi * 16 + fm) * 32 + fq];
#pragma unroll
        for (int mi = 0; mi < 4; ++mi)
#pragma unroll
            for (int ni = 0; ni < 4; ++ni)
                acc[mi][ni] = __builtin_amdgcn_mfma_f32_16x16x32_bf16(xx[mi], bh[ni], acc[mi][ni], 0, 0, 0);
#pragma unroll
        for (int ni = 0; ni < 4; ++ni)
            xx[ni] = *(const short8*)&Bl[(ncol + ni * 16 + fm) * 32 + fq];
#pragma unroll
        for (int mi = 0; mi < 4; ++mi)
#pragma unroll
            for (int ni = 0; ni < 4; ++ni)
                acc[mi][ni] = __builtin_amdgcn_mfma_f32_16x16x32_bf16(ah[mi], xx[ni], acc[mi][ni], 0, 0, 0);
    }

    int nb = n0 >> 7;  // 0,1->Q  2,3->K  4,5->V
    unsigned short* dh = (nb < 2) ? Qh : (nb < 4) ? Kh : Vh;
    unsigned short* dl = (nb < 2) ? Ql : (nb < 4) ? Kl : Vl;
    int qrow = (ln >> 4) * 4;
#pragma unroll
    for (int ni = 0; ni < 4; ++ni) {
        int col = (n0 & 255) + ncol + ni * 16 + fm;
        float bias = bqkv[n0 + ncol + ni * 16 + fm];
#pragma unroll
        for (int mi = 0; mi < 4; ++mi) {
#pragma unroll
            for (int r = 0; r < 4; ++r) {
                int m = m0 + mrow + mi * 16 + qrow + r;
                float v = acc[mi][ni][r] + bias;
                unsigned short h, l;
                split2(v, h, l);
                size_t idx = (size_t)m * 256 + col;
                dh[idx] = h; dl[idx] = l;
            }
        }
    }
}

// ---------------------------------------------------------------------------
// K1b: transpose V [win*49+tok][256] -> Vt[win][c][64] hi/lo, tok pads zeroed.
// grid 512, block 256. Coalesced 16B stores.
__global__ __launch_bounds__(256) void k_transpose_v(
    const unsigned short* __restrict__ Vh, const unsigned short* __restrict__ Vl,
    unsigned short* __restrict__ Vth, unsigned short* __restrict__ Vtl) {
    __shared__ unsigned int T[49][257];
    int win = blockIdx.x;
    int tid = threadIdx.x;
#pragma unroll 1
    for (int i = tid; i < 49 * 64; i += 256) {
        int tok = i >> 6, cq = (i & 63) * 4;
        size_t g = ((size_t)win * 49 + tok) * 256 + cq;
        ushort4 h4 = *(const ushort4*)&Vh[g];
        ushort4 l4 = *(const ushort4*)&Vl[g];
        T[tok][cq + 0] = ((unsigned)h4.x << 16) | l4.x;
        T[tok][cq + 1] = ((unsigned)h4.y << 16) | l4.y;
        T[tok][cq + 2] = ((unsigned)h4.z << 16) | l4.z;
        T[tok][cq + 3] = ((unsigned)h4.w << 16) | l4.w;
    }
    __syncthreads();
#pragma unroll 1
    for (int it = 0; it < 8; ++it) {
        int item = tid + it * 256;      // 0..2047
        int t8 = (item & 7) * 8, c = item >> 3;
        short8 hv, lv;
#pragma unroll
        for (int e = 0; e < 8; ++e) {
            int tok = t8 + e;
            unsigned v = (tok < 49) ? T[tok][c] : 0u;
            hv[e] = (short)(v >> 16);
            lv[e] = (short)(v & 0xFFFFu);
        }
        size_t o = (size_t)win * 16384 + (size_t)c * 64 + t8;
        *(short8*)&Vth[o] = hv;
        *(short8*)&Vtl[o] = lv;
    }
}

// ---------------------------------------------------------------------------
// K2: FUSED attention: QK^T (MFMA) -> register softmax -> P in LDS -> PV (MFMA)
// -> dwconv epilogue. grid 512 (win), block 256 (4 waves; wave = region for QK,
// wave = 64-channel strip for PV).
__global__ __launch_bounds__(256) void k_attn_fused(
    const unsigned short* __restrict__ Qh, const unsigned short* __restrict__ Ql,
    const unsigned short* __restrict__ Kh, const unsigned short* __restrict__ Kl,
    const unsigned short* __restrict__ Vth, const unsigned short* __restrict__ Vtl,
    const int* __restrict__ topk, const float* __restrict__ gwt,
    const float* __restrict__ dwk, const float* __restrict__ dwb,
    unsigned short* __restrict__ atth, unsigned short* __restrict__ attl) {
    __shared__ __align__(16) unsigned short Ph[64][136];
    __shared__ __align__(16) unsigned short Pl[64][136];
    __shared__ float redm[4][64];
    __shared__ float reds[4][64];
    __shared__ float gmax[64];
    __shared__ float ginv[64];
    int win = blockIdx.x, b = win >> 6;
    int tid = threadIdx.x, ln = tid & 63, wv = tid >> 6;
    int fm = ln & 15, g = ln >> 4, fq = g * 8;
    int ncol = wv * 64;

    int myreg = topk[win * 4 + wv];
    float gw = gwt[win * 4 + wv];
    float sg = SCALE * gw;
    size_t qbase = (size_t)win * 49 * 256;
    size_t kbase = (size_t)(b * 64 + myreg) * 49 * 256;

    // ---- QK^T: 64x64 per wave, 3-pass split bf16 ----
    f32x4 acc[4][4];
#pragma unroll
    for (int i = 0; i < 4; ++i)
#pragma unroll
        for (int j = 0; j < 4; ++j) acc[i][j] = (f32x4){0.f, 0.f, 0.f, 0.f};

#pragma unroll 1
    for (int kc = 0; kc < 256; kc += 32) {
        short8 ah[4], al[4], bh[4], bl[4];
#pragma unroll
        for (int mi = 0; mi < 4; ++mi) {
            size_t o = qbase + (size_t)(mi * 16 + fm) * 256 + kc + fq;
            ah[mi] = *(const short8*)&Qh[o];
            al[mi] = *(const short8*)&Ql[o];
        }
#pragma unroll
        for (int ni = 0; ni < 4; ++ni) {
            size_t o = kbase + (size_t)(ni * 16 + fm) * 256 + kc + fq;
            bh[ni] = *(const short8*)&Kh[o];
            bl[ni] = *(const short8*)&Kl[o];
        }
#pragma unroll
        for (int mi = 0; mi < 4; ++mi)
#pragma unroll
            for (int ni = 0; ni < 4; ++ni) {
                acc[mi][ni] = __builtin_amdgcn_mfma_f32_16x16x32_bf16(ah[mi], bh[ni], acc[mi][ni], 0, 0, 0);
                acc[mi][ni] = __builtin_amdgcn_mfma_f32_16x16x32_bf16(al[mi], bh[ni], acc[mi][ni], 0, 0, 0);
                acc[mi][ni] = __builtin_amdgcn_mfma_f32_16x16x32_bf16(ah[mi], bl[ni], acc[mi][ni], 0, 0, 0);
            }
    }

    // scale logits
#pragma unroll
    for (int mi = 0; mi < 4; ++mi)
#pragma unroll
        for (int ni = 0; ni < 4; ++ni) acc[mi][ni] *= sg;

    // ---- register softmax stats: per-row (w) max over valid j ----
    float rmax[4][4];
#pragma unroll
    for (int mi = 0; mi < 4; ++mi)
#pragma unroll
        for (int r = 0; r < 4; ++r) rmax[mi][r] = -3.0e38f;
#pragma unroll
    for (int mi = 0; mi < 4; ++mi)
#pragma unroll
        for (int ni = 0; ni < 4; ++ni) {
            if (ni * 16 + fm < 49) {
#pragma unroll
                for (int r = 0; r < 4; ++r)
                    rmax[mi][r] = fmaxf(rmax[mi][r], acc[mi][ni][r]);
            }
        }
#pragma unroll
    for (int off = 1; off < 16; off <<= 1)
#pragma unroll
        for (int mi = 0; mi < 4; ++mi)
#pragma unroll
            for (int r = 0; r < 4; ++r)
                rmax[mi][r] = fmaxf(rmax[mi][r], __shfl_xor(rmax[mi][r], off, 64));
    if (fm == 0) {
#pragma unroll
        for (int mi = 0; mi < 4; ++mi)
#pragma unroll
            for (int r = 0; r < 4; ++r)
                redm[wv][mi * 16 + g * 4 + r] = rmax[mi][r];
    }
    __syncthreads();
    if (tid < 64)
        gmax[tid] = fmaxf(fmaxf(redm[0][tid], redm[1][tid]),
                          fmaxf(redm[2][tid], redm[3][tid]));
    __syncthreads();

    // exp + row sums
    float gm[4][4];
#pragma unroll
    for (int mi = 0; mi < 4; ++mi)
#pragma unroll
        for (int r = 0; r < 4; ++r) gm[mi][r] = gmax[mi * 16 + g * 4 + r];
    float rsum[4][4];
#pragma unroll
    for (int mi = 0; mi < 4; ++mi)
#pragma unroll
        for (int r = 0; r < 4; ++r) rsum[mi][r] = 0.f;
#pragma unroll
    for (int mi = 0; mi < 4; ++mi)
#pragma unroll
        for (int ni = 0; ni < 4; ++ni) {
            bool valid = (ni * 16 + fm) < 49;
#pragma unroll
            for (int r = 0; r < 4; ++r) {
                float e = valid ? __expf(acc[mi][ni][r] - gm[mi][r]) : 0.f;
                acc[mi][ni][r] = e;
                rsum[mi][r] += e;
            }
        }
#pragma unroll
    for (int off = 1; off < 16; off <<= 1)
#pragma unroll
        for (int mi = 0; mi < 4; ++mi)
#pragma unroll
            for (int r = 0; r < 4; ++r)
                rsum[mi][r] += __shfl_xor(rsum[mi][r], off, 64);
    if (fm == 0) {
#pragma unroll
        for (int mi = 0; mi < 4; ++mi)
#pragma unroll
            for (int r = 0; r < 4; ++r)
                reds[wv][mi * 16 + g * 4 + r] = rsum[mi][r];
    }
    __syncthreads();
    if (tid < 64)
        ginv[tid] = 1.0f / (reds[0][tid] + reds[1][tid] + reds[2][tid] + reds[3][tid]);
    __syncthreads();
    float gi[4][4];
#pragma unroll
    for (int mi = 0; mi < 4; ++mi)
#pragma unroll
        for (int r = 0; r < 4; ++r) gi[mi][r] = ginv[mi * 16 + g * 4 + r];

    // ---- PV in two halves (regions 0,1 then 2,3); P staged in LDS bf16 hi/lo ----
    f32x4 oacc[4][4];
#pragma unroll
    for (int i = 0; i < 4; ++i)
#pragma unroll
        for (int j = 0; j < 4; ++j) oacc[i][j] = (f32x4){0.f, 0.f, 0.f, 0.f};

#pragma unroll 1
    for (int half = 0; half < 2; ++half) {
        if (half) __syncthreads();   // prior PV reads done before overwrite
        if ((wv >> 1) == half) {
            int jb = (wv & 1) * 64;
#pragma unroll
            for (int mi = 0; mi < 4; ++mi)
#pragma unroll
                for (int ni = 0; ni < 4; ++ni) {
                    int j = ni * 16 + fm;
#pragma unroll
                    for (int r = 0; r < 4; ++r) {
                        int row = mi * 16 + g * 4 + r;
                        float p = acc[mi][ni][r] * gi[mi][r] * gw;
                        unsigned short h, l;
                        split2(p, h, l);
                        Ph[row][jb + j] = h;
                        Pl[row][jb + j] = l;
                    }
                }
        }
        __syncthreads();
#pragma unroll 1
        for (int chunk = 0; chunk < 4; ++chunk) {
            int rr = half * 2 + (chunk >> 1);
            int reg2 = topk[win * 4 + rr];
            size_t vbase = (size_t)(b * 64 + reg2) * 16384;
            int tokoff = (chunk & 1) * 32;
            int jloc = (chunk >> 1) * 64 + tokoff;
            short8 ah[4], al[4], bh[4], bl[4];
#pragma unroll
            for (int mi = 0; mi < 4; ++mi) {
                ah[mi] = *(const short8*)&Ph[mi * 16 + fm][jloc + fq];
                al[mi] = *(const short8*)&Pl[mi * 16 + fm][jloc + fq];
            }
#pragma unroll
            for (int ni = 0; ni < 4; ++ni) {
                size_t o = vbase + (size_t)(ncol + ni * 16 + fm) * 64 + tokoff + fq;
                bh[ni] = *(const short8*)&Vth[o];
                bl[ni] = *(const short8*)&Vtl[o];
            }
#pragma unroll
            for (int mi = 0; mi < 4; ++mi)
#pragma unroll
                for (int ni = 0; ni < 4; ++ni) {
                    oacc[mi][ni] = __builtin_amdgcn_mfma_f32_16x16x32_bf16(ah[mi], bh[ni], oacc[mi][ni], 0, 0, 0);
                    oacc[mi][ni] = __builtin_amdgcn_mfma_f32_16x16x32_bf16(al[mi], bh[ni], oacc[mi][ni], 0, 0, 0);
                    oacc[mi][ni] = __builtin_amdgcn_mfma_f32_16x16x32_bf16(ah[mi], bl[ni], oacc[mi][ni], 0, 0, 0);
                }
        }
    }

    // ---- epilogue: dwconv on own-window V (from Vt) + bf16 hi/lo store ----
    size_t vown = (size_t)win * 16384;
#pragma unroll 1
    for (int ni = 0; ni < 4; ++ni) {
        int c = ncol + ni * 16 + fm;
        float dk[9];
#pragma unroll
        for (int t = 0; t < 9; ++t) dk[t] = dwk[(size_t)t * 256 + c];
        float db = dwb[c];
        const unsigned short* vh = Vth + vown + (size_t)c * 64;
        const unsigned short* vl = Vtl + vown + (size_t)c * 64;
#pragma unroll
        for (int mi = 0; mi < 4; ++mi) {
#pragma unroll
            for (int rr = 0; rr < 4; ++rr) {
                int w = mi * 16 + g * 4 + rr;
                if (w < 49) {
                    int py = w / 7, px = w - py * 7;
                    float vd = db;
#pragma unroll
                    for (int dy = 0; dy < 3; ++dy) {
                        int yy = py + dy - 1;
                        if (yy < 0 || yy > 6) continue;
#pragma unroll
                        for (int dx = 0; dx < 3; ++dx) {
                            int xx = px + dx - 1;
                            if (xx < 0 || xx > 6) continue;
                            int nt = yy * 7 + xx;
                            float v = b2f(vh[nt]) + b2f(vl[nt]);
                            vd += v * dk[dy * 3 + dx];
                        }
                    }
                    float o = oacc[mi][ni][rr] + vd;
                    unsigned short h, l;
                    split2(o, h, l);
                    size_t idx = ((size_t)win * 49 + w) * 256 + c;
                    atth[idx] = h;
                    attl[idx] = l;
                }
            }
        }
    }
}

// ---------------------------------------------------------------------------
// K3: proj GEMM, split-bf16 MFMA. M=25088, K=256, N=256. grid (2, 196).
__global__ __launch_bounds__(256) void k_mm_proj(
    const unsigned short* __restrict__ ahi, const unsigned short* __restrict__ alo,
    const unsigned short* __restrict__ whi, const unsigned short* __restrict__ wlo,
    const float* __restrict__ bp, float* __restrict__ out) {
    __shared__ __align__(16) unsigned short Ah[4096];
    __shared__ __align__(16) unsigned short Al[4096];
    __shared__ __align__(16) unsigned short Bh[4096];
    __shared__ __align__(16) unsigned short Bl[4096];
    int tid = threadIdx.x;
    int ln = tid & 63, wv = tid >> 6;
    int m0 = blockIdx.y * 128, n0 = blockIdx.x * 128;
    int mrow = (wv >> 1) * 64, ncol = (wv & 1) * 64;

    int lrow = ln >> 2, lseg = (ln & 3) * 8;
    const unsigned short* gA0 = ahi + (size_t)(m0 + wv * 32 + lrow) * 256 + lseg;
    const unsigned short* gA1 = gA0 + 16 * 256;
    const unsigned short* gAl0 = alo + (size_t)(m0 + wv * 32 + lrow) * 256 + lseg;
    const unsigned short* gAl1 = gAl0 + 16 * 256;
    const unsigned short* gB0 = whi + (size_t)(n0 + wv * 32 + lrow) * 256 + lseg;
    const unsigned short* gB1 = gB0 + 16 * 256;
    const unsigned short* gBl0 = wlo + (size_t)(n0 + wv * 32 + lrow) * 256 + lseg;
    const unsigned short* gBl1 = gBl0 + 16 * 256;
    unsigned short* lA0 = &Ah[(wv * 32) * 32];
    unsigned short* lA1 = &Ah[(wv * 32 + 16) * 32];
    unsigned short* lAl0 = &Al[(wv * 32) * 32];
    unsigned short* lAl1 = &Al[(wv * 32 + 16) * 32];
    unsigned short* lB0 = &Bh[(wv * 32) * 32];
    unsigned short* lB1 = &Bh[(wv * 32 + 16) * 32];
    unsigned short* lBl0 = &Bl[(wv * 32) * 32];
    unsigned short* lBl1 = &Bl[(wv * 32 + 16) * 32];

    int fm = ln & 15, fq = (ln >> 4) * 8;
    f32x4 acc[4][4];
#pragma unroll
    for (int i = 0; i < 4; ++i)
#pragma unroll
        for (int j = 0; j < 4; ++j) acc[i][j] = (f32x4){0.f, 0.f, 0.f, 0.f};

#pragma unroll 1
    for (int kc = 0; kc < 8; ++kc) {
        if (kc) __syncthreads();
        gload16(gA0, lA0); gload16(gA1, lA1);
        gload16(gAl0, lAl0); gload16(gAl1, lAl1);
        gload16(gB0, lB0); gload16(gB1, lB1);
        gload16(gBl0, lBl0); gload16(gBl1, lBl1);
        gA0 += 32; gA1 += 32; gAl0 += 32; gAl1 += 32;
        gB0 += 32; gB1 += 32; gBl0 += 32; gBl1 += 32;
        __syncthreads();

        short8 ah[4], bh[4], xx[4];
#pragma unroll
        for (int mi = 0; mi < 4; ++mi)
            ah[mi] = *(const short8*)&Ah[(mrow + mi * 16 + fm) * 32 + fq];
#pragma unroll
        for (int ni = 0; ni < 4; ++ni)
            bh[ni] = *(const short8*)&Bh[(ncol + ni * 16 + fm) * 32 + fq];
#pragma unroll
        for (int mi = 0; mi < 4; ++mi)
#pragma unroll
            for (int ni = 0; ni < 4; ++ni)
                acc[mi][ni] = __builtin_amdgcn_mfma_f32_16x16x32_bf16(ah[mi], bh[ni], acc[mi][ni], 0, 0, 0);
#pragma unroll
        for (int mi = 0; mi < 4; ++mi)
            xx[mi] = *(const short8*)&Al[(mrow + mi * 16 + fm) * 32 + fq];
#pragma unroll
        for (int mi = 0; mi < 4; ++mi)
#pragma unroll
            for (int ni = 0; ni < 4; ++ni)
                acc[mi][ni] = __builtin_amdgcn_mfma_f32_16x16x32_bf16(xx[mi], bh[ni], acc[mi][ni], 0, 0, 0);
#pragma unroll
        for (int ni = 0; ni < 4; ++ni)
            xx[ni] = *(const short8*)&Bl[(ncol + ni * 16 + fm) * 32 + fq];
#pragma unroll
        for (int mi = 0; mi < 4; ++mi)
#pragma unroll
            for (int ni = 0; ni < 4; ++ni)
                acc[mi][ni] = __builtin_amdgcn_mfma_f32_16x16x32_bf16(ah[mi], xx[ni], acc[mi][ni], 0, 0, 0);
    }

    int qrow = (ln >> 4) * 4;
#pragma unroll
    for (int mi = 0; mi < 4; ++mi) {
#pragma unroll
        for (int r = 0; r < 4; ++r) {
            int m = m0 + mrow + mi * 16 + qrow + r;
            size_t orow = (size_t)token_row_addr(m);
#pragma unroll
            for (int ni = 0; ni < 4; ++ni) {
                int col = n0 + ncol + ni * 16 + fm;
                out[orow * 256 + col] = acc[mi][ni][r] + bp[col];
            }
        }
    }
}

// ---------------------------------------------------------------------------
extern "C" void kernel_launch(void* const* d_in, const int* in_sizes, int n_in,
                              void* d_out, int out_size, void* d_ws, size_t ws_size,
                              hipStream_t stream) {
    const float* x    = (const float*)d_in[0];
    const float* wqkv = (const float*)d_in[1];
    const float* bqkv = (const float*)d_in[2];
    const float* wg1  = (const float*)d_in[3];
    const float* bg1  = (const float*)d_in[4];
    const float* wg2  = (const float*)d_in[5];
    const float* bg2  = (const float*)d_in[6];
    const float* dwk  = (const float*)d_in[7];
    const float* dwb  = (const float*)d_in[8];
    const float* wp   = (const float*)d_in[9];
    const float* bp   = (const float*)d_in[10];
    float* out = (float*)d_out;

    const size_t NTOT = (size_t)25088 * 256;     // 6,422,528
    const size_t VTSZ = (size_t)512 * 256 * 64;  // 8,388,608
    unsigned short* Qh  = (unsigned short*)d_ws;
    unsigned short* Ql  = Qh + NTOT;
    unsigned short* Kh  = Ql + NTOT;
    unsigned short* Kl  = Kh + NTOT;
    unsigned short* Vh  = Kl + NTOT;
    unsigned short* Vl  = Vh + NTOT;
    unsigned short* Vth = Vl + NTOT;
    unsigned short* Vtl = Vth + VTSZ;
    unsigned short* XH  = Vtl + VTSZ;   // x bf16 windowed; reused as ATT hi
    unsigned short* XL  = XH + NTOT;    // reused as ATT lo
    unsigned short* WQH = XL + NTOT;
    unsigned short* WQL = WQH + 768 * 256;
    unsigned short* WPH = WQL + 768 * 256;
    unsigned short* WPL = WPH + 256 * 256;
    float* XR   = (float*)(WPL + 256 * 256);
    float* QKVR = XR + 512 * 256;
    float* SIG  = QKVR + 512 * 768;
    float* GWT  = SIG + 1024;
    int*   TOPK = (int*)(GWT + 2048);

    hipLaunchKernelGGL(k_cvt_x, dim3(25088), dim3(256), 0, stream, x, XH, XL);
    hipLaunchKernelGGL(k_cvt_w, dim3(768), dim3(256), 0, stream, wqkv, 768, WQH, WQL);
    hipLaunchKernelGGL(k_cvt_w, dim3(256), dim3(256), 0, stream, wp, 256, WPH, WPL);
    hipLaunchKernelGGL(k_region_mean, dim3(512), dim3(256), 0, stream, x, XR);
    hipLaunchKernelGGL(k_region_qkv, dim3(512), dim3(256), 0, stream, XR, wqkv, bqkv, QKVR);
    hipLaunchKernelGGL(k_gating, dim3(512), dim3(64), 0, stream, QKVR, wg1, bg1, wg2, bg2, SIG);
    hipLaunchKernelGGL(k_topk_gauss, dim3(512), dim3(64), 0, stream, QKVR, SIG, TOPK, GWT);
    hipLaunchKernelGGL(k_mm_qkv, dim3(6, 196), dim3(256), 0, stream,
                       XH, XL, WQH, WQL, bqkv, Qh, Ql, Kh, Kl, Vh, Vl);
    hipLaunchKernelGGL(k_transpose_v, dim3(512), dim3(256), 0, stream, Vh, Vl, Vth, Vtl);
    hipLaunchKernelGGL(k_attn_fused, dim3(512), dim3(256), 0, stream,
                       Qh, Ql, Kh, Kl, Vth, Vtl, TOPK, GWT, dwk, dwb, XH, XL);
    hipLaunchKernelGGL(k_mm_proj, dim3(2, 196), dim3(256), 0, stream,
                       XH, XL, WPH, WPL, bp, out);
}

// Round 7
// 436.088 us; speedup vs baseline: 1.6862x; 1.1850x over previous
//
#include <hip/hip_runtime.h>
#include <math.h>

#define SCALE 0.17677669529663687f  /* (256/8)^-0.5 */

typedef short short8 __attribute__((ext_vector_type(8)));
typedef float f32x4 __attribute__((ext_vector_type(4)));

// ---------------------------------------------------------------------------
__device__ __forceinline__ int token_row_addr(int m) {
    int b = m / 3136;
    int rem = m - b * 3136;
    int s = rem / 49;
    int tok = rem - s * 49;
    int h = (s >> 3) * 7 + tok / 7;
    int w = (s & 7) * 7 + (tok % 7);
    return (b * 56 + h) * 56 + w;
}

__device__ __forceinline__ void split2(float x, unsigned short& h, unsigned short& l) {
    unsigned int u = __float_as_uint(x);
    h = (unsigned short)(u >> 16);
    float hf = __uint_as_float(u & 0xFFFF0000u);
    l = (unsigned short)(__float_as_uint(x - hf) >> 16);
}

__device__ __forceinline__ unsigned int pack2(float x) {
    unsigned short h, l;
    split2(x, h, l);
    return ((unsigned int)h << 16) | l;
}

__device__ __forceinline__ float b2f(unsigned short u) {
    return __uint_as_float(((unsigned int)u) << 16);
}

// unpack 8 packed u32 -> hi/lo bf16 fragments
__device__ __forceinline__ void unpack_u4(uint4 a, uint4 b, short8& h, short8& l) {
    h[0] = (short)(a.x >> 16); l[0] = (short)(a.x & 0xFFFFu);
    h[1] = (short)(a.y >> 16); l[1] = (short)(a.y & 0xFFFFu);
    h[2] = (short)(a.z >> 16); l[2] = (short)(a.z & 0xFFFFu);
    h[3] = (short)(a.w >> 16); l[3] = (short)(a.w & 0xFFFFu);
    h[4] = (short)(b.x >> 16); l[4] = (short)(b.x & 0xFFFFu);
    h[5] = (short)(b.y >> 16); l[5] = (short)(b.y & 0xFFFFu);
    h[6] = (short)(b.z >> 16); l[6] = (short)(b.z & 0xFFFFu);
    h[7] = (short)(b.w >> 16); l[7] = (short)(b.w & 0xFFFFu);
}

__device__ __forceinline__ void load_unpack8(const unsigned int* g, short8& h, short8& l) {
    uint4 a = *(const uint4*)g;
    uint4 b = *(const uint4*)(g + 4);
    unpack_u4(a, b, h, l);
}

// async global->LDS 16B per lane
__device__ __forceinline__ void gload16(const unsigned short* g, unsigned short* l) {
    __builtin_amdgcn_global_load_lds(
        (const __attribute__((address_space(1))) unsigned int*)g,
        (__attribute__((address_space(3))) unsigned int*)l, 16, 0, 0);
}

// ---------------------------------------------------------------------------
// converters (x and weights stay hi/lo separate: they feed LDS-staged GEMMs)
__global__ void k_cvt_x(const float* __restrict__ x, unsigned short* __restrict__ xhi,
                        unsigned short* __restrict__ xlo) {
    int m = blockIdx.x;
    int k = threadIdx.x;
    float v = x[(size_t)token_row_addr(m) * 256 + k];
    unsigned short h, l;
    split2(v, h, l);
    xhi[(size_t)m * 256 + k] = h;
    xlo[(size_t)m * 256 + k] = l;
}

__global__ void k_cvt_w(const float* __restrict__ w, int ncols,
                        unsigned short* __restrict__ whi, unsigned short* __restrict__ wlo) {
    int n = blockIdx.x;
    int k = threadIdx.x;
    float v = w[(size_t)k * ncols + n];
    unsigned short h, l;
    split2(v, h, l);
    whi[(size_t)n * 256 + k] = h;
    wlo[(size_t)n * 256 + k] = l;
}

// ---------------------------------------------------------------------------
// K0a..K0d: fp32 region path (unchanged)
__global__ void k_region_mean(const float* __restrict__ x, float* __restrict__ xr) {
    int blk = blockIdx.x;
    int b = blk >> 6, s = blk & 63;
    int c = threadIdx.x;
    int hy0 = (s >> 3) * 7, wx0 = (s & 7) * 7;
    const float* xb = x + ((size_t)b * 56 * 56) * 256 + c;
    float sum = 0.f;
#pragma unroll 1
    for (int t = 0; t < 49; ++t) {
        int h = hy0 + t / 7, w = wx0 + (t % 7);
        sum += xb[(size_t)(h * 56 + w) * 256];
    }
    xr[(size_t)blk * 256 + c] = sum * (1.0f / 49.0f);
}

__global__ void k_region_qkv(const float* __restrict__ xr, const float* __restrict__ wqkv,
                             const float* __restrict__ bqkv, float* __restrict__ qkvr) {
    __shared__ float xs[256];
    int blk = blockIdx.x;
    int t = threadIdx.x;
    xs[t] = xr[(size_t)blk * 256 + t];
    __syncthreads();
    float a0 = 0.f, a1 = 0.f, a2 = 0.f;
#pragma unroll 4
    for (int k = 0; k < 256; ++k) {
        float xv = xs[k];
        const float* wrow = wqkv + (size_t)k * 768;
        a0 += xv * wrow[t];
        a1 += xv * wrow[t + 256];
        a2 += xv * wrow[t + 512];
    }
    float* o = qkvr + (size_t)blk * 768;
    o[t]       = a0 + bqkv[t];
    o[t + 256] = a1 + bqkv[t + 256];
    o[t + 512] = a2 + bqkv[t + 512];
}

__global__ void k_gating(const float* __restrict__ qkvr, const float* __restrict__ wg1,
                         const float* __restrict__ bg1, const float* __restrict__ wg2,
                         const float* __restrict__ bg2, float* __restrict__ sig) {
    __shared__ float hs[64];
    int blk = blockIdx.x;
    int j = threadIdx.x;
    const float* qr = qkvr + (size_t)blk * 768;
    float acc = bg1[j];
#pragma unroll 4
    for (int k = 0; k < 256; ++k) acc += qr[k] * wg1[(size_t)k * 64 + j];
    hs[j] = fmaxf(acc, 0.f);
    __syncthreads();
    if (j < 2) {
        float gp = bg2[j];
#pragma unroll 1
        for (int m = 0; m < 64; ++m) gp += hs[m] * wg2[m * 2 + j];
        float sp = fmaxf(gp, 0.f) + log1pf(expf(-fabsf(gp)));
        sig[blk * 2 + j] = sp + 0.5f;
    }
}

__global__ void k_topk_gauss(const float* __restrict__ qkvr, const float* __restrict__ sig,
                             int* __restrict__ topk, float* __restrict__ gwt) {
    __shared__ float A[64];
    __shared__ float G[64];
    __shared__ int idxs[4];
    __shared__ float gsum_s;
    int blk = blockIdx.x;
    int b = blk >> 6, s = blk & 63;
    int z = threadIdx.x;
    const float* qr = qkvr + (size_t)blk * 768;
    const float* kr = qkvr + (size_t)(b * 64 + z) * 768 + 256;
    float acc = 0.f;
#pragma unroll 4
    for (int k = 0; k < 256; k += 4) {
        float4 q4 = *(const float4*)(qr + k);
        float4 k4 = *(const float4*)(kr + k);
        acc += q4.x * k4.x + q4.y * k4.y + q4.z * k4.z + q4.w * k4.w;
    }
    A[z] = acc * SCALE;
    float s0 = sig[blk * 2 + 0], s1 = sig[blk * 2 + 1];
    float dx = (float)((z & 7) - (s & 7));
    float dy = (float)((z >> 3) - (s >> 3));
    float t0 = dx / s0, t1 = dy / s1;
    float zz = t0 * t0 + t1 * t1;
    G[z] = expf(-0.5f * zz);
    __syncthreads();
    if (z == 0) {
        float gs = 0.f;
        for (int m = 0; m < 64; ++m) gs += G[m];
        gsum_s = gs + 1e-6f;
        for (int it = 0; it < 4; ++it) {
            int best = 0;
            float bv = A[0];
            for (int m = 1; m < 64; ++m) {
                if (A[m] > bv) { bv = A[m]; best = m; }
            }
            idxs[it] = best;
            A[best] = -3.0e38f;
        }
    }
    __syncthreads();
    if (z < 4) {
        int id = idxs[z];
        topk[blk * 4 + z] = id;
        gwt[blk * 4 + z] = G[id] / gsum_s;
    }
}

// ---------------------------------------------------------------------------
// K1: qkv GEMM, split-bf16 MFMA, 128x128 tile, BK=32. grid (6, 196).
// Epilogue: Q,K,V packed [hi|lo] u32 [token][256], 4B/lane 64B-segment stores.
__global__ __launch_bounds__(256) void k_mm_qkv(
    const unsigned short* __restrict__ xhi, const unsigned short* __restrict__ xlo,
    const unsigned short* __restrict__ whi, const unsigned short* __restrict__ wlo,
    const float* __restrict__ bqkv,
    unsigned int* __restrict__ Qp, unsigned int* __restrict__ Kp,
    unsigned int* __restrict__ Vp) {
    __shared__ __align__(16) unsigned short Ah[4096];
    __shared__ __align__(16) unsigned short Al[4096];
    __shared__ __align__(16) unsigned short Bh[4096];
    __shared__ __align__(16) unsigned short Bl[4096];
    int tid = threadIdx.x;
    int ln = tid & 63, wv = tid >> 6;
    int m0 = blockIdx.y * 128, n0 = blockIdx.x * 128;
    int mrow = (wv >> 1) * 64, ncol = (wv & 1) * 64;

    int lrow = ln >> 2, lseg = (ln & 3) * 8;
    const unsigned short* gA0 = xhi + (size_t)(m0 + wv * 32 + lrow) * 256 + lseg;
    const unsigned short* gA1 = gA0 + 16 * 256;
    const unsigned short* gAl0 = xlo + (size_t)(m0 + wv * 32 + lrow) * 256 + lseg;
    const unsigned short* gAl1 = gAl0 + 16 * 256;
    const unsigned short* gB0 = whi + (size_t)(n0 + wv * 32 + lrow) * 256 + lseg;
    const unsigned short* gB1 = gB0 + 16 * 256;
    const unsigned short* gBl0 = wlo + (size_t)(n0 + wv * 32 + lrow) * 256 + lseg;
    const unsigned short* gBl1 = gBl0 + 16 * 256;
    unsigned short* lA0 = &Ah[(wv * 32) * 32];
    unsigned short* lA1 = &Ah[(wv * 32 + 16) * 32];
    unsigned short* lAl0 = &Al[(wv * 32) * 32];
    unsigned short* lAl1 = &Al[(wv * 32 + 16) * 32];
    unsigned short* lB0 = &Bh[(wv * 32) * 32];
    unsigned short* lB1 = &Bh[(wv * 32 + 16) * 32];
    unsigned short* lBl0 = &Bl[(wv * 32) * 32];
    unsigned short* lBl1 = &Bl[(wv * 32 + 16) * 32];

    int fm = ln & 15, fq = (ln >> 4) * 8;
    f32x4 acc[4][4];
#pragma unroll
    for (int i = 0; i < 4; ++i)
#pragma unroll
        for (int j = 0; j < 4; ++j) acc[i][j] = (f32x4){0.f, 0.f, 0.f, 0.f};

#pragma unroll 1
    for (int kc = 0; kc < 8; ++kc) {
        if (kc) __syncthreads();
        gload16(gA0, lA0); gload16(gA1, lA1);
        gload16(gAl0, lAl0); gload16(gAl1, lAl1);
        gload16(gB0, lB0); gload16(gB1, lB1);
        gload16(gBl0, lBl0); gload16(gBl1, lBl1);
        gA0 += 32; gA1 += 32; gAl0 += 32; gAl1 += 32;
        gB0 += 32; gB1 += 32; gBl0 += 32; gBl1 += 32;
        __syncthreads();

        short8 ah[4], bh[4], xx[4];
#pragma unroll
        for (int mi = 0; mi < 4; ++mi)
            ah[mi] = *(const short8*)&Ah[(mrow + mi * 16 + fm) * 32 + fq];
#pragma unroll
        for (int ni = 0; ni < 4; ++ni)
            bh[ni] = *(const short8*)&Bh[(ncol + ni * 16 + fm) * 32 + fq];
#pragma unroll
        for (int mi = 0; mi < 4; ++mi)
#pragma unroll
            for (int ni = 0; ni < 4; ++ni)
                acc[mi][ni] = __builtin_amdgcn_mfma_f32_16x16x32_bf16(ah[mi], bh[ni], acc[mi][ni], 0, 0, 0);
#pragma unroll
        for (int mi = 0; mi < 4; ++mi)
            xx[mi] = *(const short8*)&Al[(mrow + mi * 16 + fm) * 32 + fq];
#pragma unroll
        for (int mi = 0; mi < 4; ++mi)
#pragma unroll
            for (int ni = 0; ni < 4; ++ni)
                acc[mi][ni] = __builtin_amdgcn_mfma_f32_16x16x32_bf16(xx[mi], bh[ni], acc[mi][ni], 0, 0, 0);
#pragma unroll
        for (int ni = 0; ni < 4; ++ni)
            xx[ni] = *(const short8*)&Bl[(ncol + ni * 16 + fm) * 32 + fq];
#pragma unroll
        for (int mi = 0; mi < 4; ++mi)
#pragma unroll
            for (int ni = 0; ni < 4; ++ni)
                acc[mi][ni] = __builtin_amdgcn_mfma_f32_16x16x32_bf16(ah[mi], xx[ni], acc[mi][ni], 0, 0, 0);
    }

    int nb = n0 >> 7;  // 0,1->Q  2,3->K  4,5->V
    unsigned int* dst = (nb < 2) ? Qp : (nb < 4) ? Kp : Vp;
    int qrow = (ln >> 4) * 4;
#pragma unroll
    for (int ni = 0; ni < 4; ++ni) {
        int col = (n0 & 255) + ncol + ni * 16 + fm;
        float bias = bqkv[n0 + ncol + ni * 16 + fm];
#pragma unroll
        for (int mi = 0; mi < 4; ++mi) {
#pragma unroll
            for (int r = 0; r < 4; ++r) {
                int m = m0 + mrow + mi * 16 + qrow + r;
                dst[(size_t)m * 256 + col] = pack2(acc[mi][ni][r] + bias);
            }
        }
    }
}

// ---------------------------------------------------------------------------
// K1b: transpose Vp [win*49+tok][256] -> Vtp[win][c][64] packed, pads zeroed.
__global__ __launch_bounds__(256) void k_transpose_v(
    const unsigned int* __restrict__ Vp, unsigned int* __restrict__ Vtp) {
    __shared__ unsigned int T[49][257];
    int win = blockIdx.x;
    int tid = threadIdx.x;
#pragma unroll 1
    for (int i = tid; i < 49 * 64; i += 256) {
        int tok = i >> 6, cq = (i & 63) * 4;
        uint4 v = *(const uint4*)&Vp[((size_t)win * 49 + tok) * 256 + cq];
        T[tok][cq + 0] = v.x;
        T[tok][cq + 1] = v.y;
        T[tok][cq + 2] = v.z;
        T[tok][cq + 3] = v.w;
    }
    __syncthreads();
#pragma unroll 1
    for (int it = 0; it < 8; ++it) {
        int item = tid + it * 256;     // 0..2047 : c = item>>3, t8 = (item&7)*8
        int c = item >> 3, t8 = (item & 7) * 8;
        uint4 o0, o1;
        o0.x = (t8 + 0 < 49) ? T[t8 + 0][c] : 0u;
        o0.y = (t8 + 1 < 49) ? T[t8 + 1][c] : 0u;
        o0.z = (t8 + 2 < 49) ? T[t8 + 2][c] : 0u;
        o0.w = (t8 + 3 < 49) ? T[t8 + 3][c] : 0u;
        o1.x = (t8 + 4 < 49) ? T[t8 + 4][c] : 0u;
        o1.y = (t8 + 5 < 49) ? T[t8 + 5][c] : 0u;
        o1.z = (t8 + 6 < 49) ? T[t8 + 6][c] : 0u;
        o1.w = (t8 + 7 < 49) ? T[t8 + 7][c] : 0u;
        size_t o = (size_t)win * 16384 + (size_t)c * 64 + t8;
        *(uint4*)&Vtp[o] = o0;
        *(uint4*)&Vtp[o + 4] = o1;
    }
}

// ---------------------------------------------------------------------------
// K2a: QK^T (3-pass MFMA from packed Q/K) + register softmax + packed P store.
// grid 512, block 256 (wave = region). P layout [win][w 64][j 256] u32.
__global__ __launch_bounds__(256) void k_attn_logits2(
    const unsigned int* __restrict__ Qp, const unsigned int* __restrict__ Kp,
    const int* __restrict__ topk, const float* __restrict__ gwt,
    unsigned int* __restrict__ Pp) {
    __shared__ float redm[4][64];
    __shared__ float reds[4][64];
    __shared__ float gmax[64];
    __shared__ float ginv[64];
    int win = blockIdx.x, b = win >> 6;
    int tid = threadIdx.x, ln = tid & 63, wv = tid >> 6;
    int fm = ln & 15, g = ln >> 4, fq = g * 8;

    int myreg = topk[win * 4 + wv];
    float gw = gwt[win * 4 + wv];
    float sg = SCALE * gw;
    size_t qbase = (size_t)win * 49 * 256;
    size_t kbase = (size_t)(b * 64 + myreg) * 49 * 256;

    f32x4 acc[4][4];
#pragma unroll
    for (int i = 0; i < 4; ++i)
#pragma unroll
        for (int j = 0; j < 4; ++j) acc[i][j] = (f32x4){0.f, 0.f, 0.f, 0.f};

#pragma unroll 1
    for (int kc = 0; kc < 256; kc += 32) {
        short8 ah[4], al[4], bh[4], bl[4];
#pragma unroll
        for (int mi = 0; mi < 4; ++mi)
            load_unpack8(&Qp[qbase + (size_t)(mi * 16 + fm) * 256 + kc + fq], ah[mi], al[mi]);
#pragma unroll
        for (int ni = 0; ni < 4; ++ni)
            load_unpack8(&Kp[kbase + (size_t)(ni * 16 + fm) * 256 + kc + fq], bh[ni], bl[ni]);
#pragma unroll
        for (int mi = 0; mi < 4; ++mi)
#pragma unroll
            for (int ni = 0; ni < 4; ++ni) {
                acc[mi][ni] = __builtin_amdgcn_mfma_f32_16x16x32_bf16(ah[mi], bh[ni], acc[mi][ni], 0, 0, 0);
                acc[mi][ni] = __builtin_amdgcn_mfma_f32_16x16x32_bf16(al[mi], bh[ni], acc[mi][ni], 0, 0, 0);
                acc[mi][ni] = __builtin_amdgcn_mfma_f32_16x16x32_bf16(ah[mi], bl[ni], acc[mi][ni], 0, 0, 0);
            }
    }

#pragma unroll
    for (int mi = 0; mi < 4; ++mi)
#pragma unroll
        for (int ni = 0; ni < 4; ++ni) acc[mi][ni] *= sg;

    // per-row max (valid cols only) -> cross-wave reduce
    float rmax[4][4];
#pragma unroll
    for (int mi = 0; mi < 4; ++mi)
#pragma unroll
        for (int r = 0; r < 4; ++r) rmax[mi][r] = -3.0e38f;
#pragma unroll
    for (int mi = 0; mi < 4; ++mi)
#pragma unroll
        for (int ni = 0; ni < 4; ++ni) {
            if (ni * 16 + fm < 49) {
#pragma unroll
                for (int r = 0; r < 4; ++r)
                    rmax[mi][r] = fmaxf(rmax[mi][r], acc[mi][ni][r]);
            }
        }
#pragma unroll
    for (int off = 1; off < 16; off <<= 1)
#pragma unroll
        for (int mi = 0; mi < 4; ++mi)
#pragma unroll
            for (int r = 0; r < 4; ++r)
                rmax[mi][r] = fmaxf(rmax[mi][r], __shfl_xor(rmax[mi][r], off, 64));
    if (fm == 0) {
#pragma unroll
        for (int mi = 0; mi < 4; ++mi)
#pragma unroll
            for (int r = 0; r < 4; ++r)
                redm[wv][mi * 16 + g * 4 + r] = rmax[mi][r];
    }
    __syncthreads();
    if (tid < 64)
        gmax[tid] = fmaxf(fmaxf(redm[0][tid], redm[1][tid]),
                          fmaxf(redm[2][tid], redm[3][tid]));
    __syncthreads();

    float gm[4][4];
#pragma unroll
    for (int mi = 0; mi < 4; ++mi)
#pragma unroll
        for (int r = 0; r < 4; ++r) gm[mi][r] = gmax[mi * 16 + g * 4 + r];
    float rsum[4][4];
#pragma unroll
    for (int mi = 0; mi < 4; ++mi)
#pragma unroll
        for (int r = 0; r < 4; ++r) rsum[mi][r] = 0.f;
#pragma unroll
    for (int mi = 0; mi < 4; ++mi)
#pragma unroll
        for (int ni = 0; ni < 4; ++ni) {
            bool valid = (ni * 16 + fm) < 49;
#pragma unroll
            for (int r = 0; r < 4; ++r) {
                float e = valid ? __expf(acc[mi][ni][r] - gm[mi][r]) : 0.f;
                acc[mi][ni][r] = e;
                rsum[mi][r] += e;
            }
        }
#pragma unroll
    for (int off = 1; off < 16; off <<= 1)
#pragma unroll
        for (int mi = 0; mi < 4; ++mi)
#pragma unroll
            for (int r = 0; r < 4; ++r)
                rsum[mi][r] += __shfl_xor(rsum[mi][r], off, 64);
    if (fm == 0) {
#pragma unroll
        for (int mi = 0; mi < 4; ++mi)
#pragma unroll
            for (int r = 0; r < 4; ++r)
                reds[wv][mi * 16 + g * 4 + r] = rsum[mi][r];
    }
    __syncthreads();
    if (tid < 64)
        ginv[tid] = 1.0f / (reds[0][tid] + reds[1][tid] + reds[2][tid] + reds[3][tid]);
    __syncthreads();

    // packed P store: 4B/lane, 16-lane 64B segments
    size_t pbase = (size_t)win * 16384 + wv * 64;
#pragma unroll
    for (int mi = 0; mi < 4; ++mi) {
#pragma unroll
        for (int r = 0; r < 4; ++r) {
            int row = mi * 16 + g * 4 + r;
            float giv = (row < 49) ? ginv[row] * gw : 0.f;
#pragma unroll
            for (int ni = 0; ni < 4; ++ni) {
                float p = acc[mi][ni][r] * giv;
                Pp[pbase + (size_t)row * 256 + ni * 16 + fm] = pack2(p);
            }
        }
    }
}

// ---------------------------------------------------------------------------
// K2b: PV (3-pass MFMA from packed P/Vt) + fused dwconv; ATT packed store.
// grid 512, block 256 (wave = 64-channel strip).
__global__ __launch_bounds__(256) void k_attn_pv2(
    const unsigned int* __restrict__ Pp, const unsigned int* __restrict__ Vtp,
    const int* __restrict__ topk, const float* __restrict__ dwk,
    const float* __restrict__ dwb, unsigned int* __restrict__ ATTp) {
    int win = blockIdx.x, b = win >> 6;
    int tid = threadIdx.x, ln = tid & 63, wv = tid >> 6;
    int fm = ln & 15, g = ln >> 4, fq = g * 8;
    int ncol = wv * 64;
    size_t pbase = (size_t)win * 16384;

    f32x4 oacc[4][4];
#pragma unroll
    for (int i = 0; i < 4; ++i)
#pragma unroll
        for (int j = 0; j < 4; ++j) oacc[i][j] = (f32x4){0.f, 0.f, 0.f, 0.f};

#pragma unroll 1
    for (int r = 0; r < 4; ++r) {
        int reg = topk[win * 4 + r];
        size_t vbase = (size_t)(b * 64 + reg) * 16384;
#pragma unroll
        for (int half = 0; half < 2; ++half) {
            int kc = r * 64 + half * 32;
            int tokoff = half * 32;
            short8 ah[4], al[4], bh[4], bl[4];
#pragma unroll
            for (int mi = 0; mi < 4; ++mi)
                load_unpack8(&Pp[pbase + (size_t)(mi * 16 + fm) * 256 + kc + fq], ah[mi], al[mi]);
#pragma unroll
            for (int ni = 0; ni < 4; ++ni)
                load_unpack8(&Vtp[vbase + (size_t)(ncol + ni * 16 + fm) * 64 + tokoff + fq], bh[ni], bl[ni]);
#pragma unroll
            for (int mi = 0; mi < 4; ++mi)
#pragma unroll
                for (int ni = 0; ni < 4; ++ni) {
                    oacc[mi][ni] = __builtin_amdgcn_mfma_f32_16x16x32_bf16(ah[mi], bh[ni], oacc[mi][ni], 0, 0, 0);
                    oacc[mi][ni] = __builtin_amdgcn_mfma_f32_16x16x32_bf16(al[mi], bh[ni], oacc[mi][ni], 0, 0, 0);
                    oacc[mi][ni] = __builtin_amdgcn_mfma_f32_16x16x32_bf16(ah[mi], bl[ni], oacc[mi][ni], 0, 0, 0);
                }
        }
    }

    // epilogue: dwconv on own-window V (packed Vt, contiguous tok) + packed store
    size_t vown = (size_t)win * 16384;
#pragma unroll 1
    for (int ni = 0; ni < 4; ++ni) {
        int c = ncol + ni * 16 + fm;
        float dk[9];
#pragma unroll
        for (int t = 0; t < 9; ++t) dk[t] = dwk[(size_t)t * 256 + c];
        float db = dwb[c];
        const unsigned int* vp = Vtp + vown + (size_t)c * 64;
#pragma unroll
        for (int mi = 0; mi < 4; ++mi) {
#pragma unroll
            for (int rr = 0; rr < 4; ++rr) {
                int w = mi * 16 + g * 4 + rr;
                if (w < 49) {
                    int py = w / 7, px = w - py * 7;
                    float vd = db;
#pragma unroll
                    for (int dy = 0; dy < 3; ++dy) {
                        int yy = py + dy - 1;
                        if (yy < 0 || yy > 6) continue;
#pragma unroll
                        for (int dx = 0; dx < 3; ++dx) {
                            int xx = px + dx - 1;
                            if (xx < 0 || xx > 6) continue;
                            int nt = yy * 7 + xx;
                            unsigned int u = vp[nt];
                            float v = b2f((unsigned short)(u >> 16)) + b2f((unsigned short)(u & 0xFFFFu));
                            vd += v * dk[dy * 3 + dx];
                        }
                    }
                    ATTp[((size_t)win * 49 + w) * 256 + c] = pack2(oacc[mi][ni][rr] + vd);
                }
            }
        }
    }
}

// ---------------------------------------------------------------------------
// K3: proj GEMM, split-bf16 MFMA. A = packed ATT staged into padded LDS
// ([128][36] u32, stride 36 => 2-way-free bank pattern). grid (2, 196).
__global__ __launch_bounds__(256) void k_mm_proj(
    const unsigned int* __restrict__ Ap,
    const unsigned short* __restrict__ whi, const unsigned short* __restrict__ wlo,
    const float* __restrict__ bp, float* __restrict__ out) {
    __shared__ __align__(16) unsigned int As[128 * 36];
    __shared__ __align__(16) unsigned short Bh[4096];
    __shared__ __align__(16) unsigned short Bl[4096];
    int tid = threadIdx.x;
    int ln = tid & 63, wv = tid >> 6;
    int m0 = blockIdx.y * 128, n0 = blockIdx.x * 128;
    int mrow = (wv >> 1) * 64, ncol = (wv & 1) * 64;

    int lrow = ln >> 2, lseg = (ln & 3) * 8;
    const unsigned short* gB0 = whi + (size_t)(n0 + wv * 32 + lrow) * 256 + lseg;
    const unsigned short* gB1 = gB0 + 16 * 256;
    const unsigned short* gBl0 = wlo + (size_t)(n0 + wv * 32 + lrow) * 256 + lseg;
    const unsigned short* gBl1 = gBl0 + 16 * 256;
    unsigned short* lB0 = &Bh[(wv * 32) * 32];
    unsigned short* lB1 = &Bh[(wv * 32 + 16) * 32];
    unsigned short* lBl0 = &Bl[(wv * 32) * 32];
    unsigned short* lBl1 = &Bl[(wv * 32 + 16) * 32];

    // A staging mapping: 8 rows per wave-instr, 4 iters -> 32 rows per wave
    int arow = ln >> 3, akk = (ln & 7) * 4;

    int fm = ln & 15, fq = (ln >> 4) * 8;
    f32x4 acc[4][4];
#pragma unroll
    for (int i = 0; i < 4; ++i)
#pragma unroll
        for (int j = 0; j < 4; ++j) acc[i][j] = (f32x4){0.f, 0.f, 0.f, 0.f};

#pragma unroll 1
    for (int kc = 0; kc < 8; ++kc) {
        if (kc) __syncthreads();
        gload16(gB0, lB0); gload16(gB1, lB1);
        gload16(gBl0, lBl0); gload16(gBl1, lBl1);
        gB0 += 32; gB1 += 32; gBl0 += 32; gBl1 += 32;
#pragma unroll
        for (int it = 0; it < 4; ++it) {
            int row = wv * 32 + it * 8 + arow;
            uint4 v = *(const uint4*)&Ap[(size_t)(m0 + row) * 256 + kc * 32 + akk];
            *(uint4*)&As[row * 36 + akk] = v;
        }
        __syncthreads();

        short8 ah[4], al[4], bh[4], xx[4];
#pragma unroll
        for (int mi = 0; mi < 4; ++mi) {
            const unsigned int* p = &As[(mrow + mi * 16 + fm) * 36 + fq];
            unpack_u4(*(const uint4*)p, *(const uint4*)(p + 4), ah[mi], al[mi]);
        }
#pragma unroll
        for (int ni = 0; ni < 4; ++ni)
            bh[ni] = *(const short8*)&Bh[(ncol + ni * 16 + fm) * 32 + fq];
#pragma unroll
        for (int mi = 0; mi < 4; ++mi)
#pragma unroll
            for (int ni = 0; ni < 4; ++ni)
                acc[mi][ni] = __builtin_amdgcn_mfma_f32_16x16x32_bf16(ah[mi], bh[ni], acc[mi][ni], 0, 0, 0);
#pragma unroll
        for (int mi = 0; mi < 4; ++mi)
#pragma unroll
            for (int ni = 0; ni < 4; ++ni)
                acc[mi][ni] = __builtin_amdgcn_mfma_f32_16x16x32_bf16(al[mi], bh[ni], acc[mi][ni], 0, 0, 0);
#pragma unroll
        for (int ni = 0; ni < 4; ++ni)
            xx[ni] = *(const short8*)&Bl[(ncol + ni * 16 + fm) * 32 + fq];
#pragma unroll
        for (int mi = 0; mi < 4; ++mi)
#pragma unroll
            for (int ni = 0; ni < 4; ++ni)
                acc[mi][ni] = __builtin_amdgcn_mfma_f32_16x16x32_bf16(ah[mi], xx[ni], acc[mi][ni], 0, 0, 0);
    }

    int qrow = (ln >> 4) * 4;
#pragma unroll
    for (int mi = 0; mi < 4; ++mi) {
#pragma unroll
        for (int r = 0; r < 4; ++r) {
            int m = m0 + mrow + mi * 16 + qrow + r;
            size_t orow = (size_t)token_row_addr(m);
#pragma unroll
            for (int ni = 0; ni < 4; ++ni) {
                int col = n0 + ncol + ni * 16 + fm;
                out[orow * 256 + col] = acc[mi][ni][r] + bp[col];
            }
        }
    }
}

// ---------------------------------------------------------------------------
extern "C" void kernel_launch(void* const* d_in, const int* in_sizes, int n_in,
                              void* d_out, int out_size, void* d_ws, size_t ws_size,
                              hipStream_t stream) {
    const float* x    = (const float*)d_in[0];
    const float* wqkv = (const float*)d_in[1];
    const float* bqkv = (const float*)d_in[2];
    const float* wg1  = (const float*)d_in[3];
    const float* bg1  = (const float*)d_in[4];
    const float* wg2  = (const float*)d_in[5];
    const float* bg2  = (const float*)d_in[6];
    const float* dwk  = (const float*)d_in[7];
    const float* dwb  = (const float*)d_in[8];
    const float* wp   = (const float*)d_in[9];
    const float* bp   = (const float*)d_in[10];
    float* out = (float*)d_out;

    const size_t NTOT = (size_t)25088 * 256;     // 6,422,528
    const size_t VTSZ = (size_t)512 * 256 * 64;  // 8,388,608
    unsigned int* Qp  = (unsigned int*)d_ws;
    unsigned int* Kp  = Qp + NTOT;
    unsigned int* Vp  = Kp + NTOT;
    unsigned int* Vtp = Vp + NTOT;
    unsigned int* Pp  = Vtp + VTSZ;
    unsigned short* XH = (unsigned short*)(Pp + VTSZ);  // x bf16 hi; later ATTp
    unsigned short* XL = XH + NTOT;                     // x bf16 lo
    unsigned int* ATTp = (unsigned int*)XH;             // alias (x dead after qkv)
    unsigned short* WQH = XL + NTOT;
    unsigned short* WQL = WQH + 768 * 256;
    unsigned short* WPH = WQL + 768 * 256;
    unsigned short* WPL = WPH + 256 * 256;
    float* XR   = (float*)(WPL + 256 * 256);
    float* QKVR = XR + 512 * 256;
    float* SIG  = QKVR + 512 * 768;
    float* GWT  = SIG + 1024;
    int*   TOPK = (int*)(GWT + 2048);

    hipLaunchKernelGGL(k_cvt_x, dim3(25088), dim3(256), 0, stream, x, XH, XL);
    hipLaunchKernelGGL(k_cvt_w, dim3(768), dim3(256), 0, stream, wqkv, 768, WQH, WQL);
    hipLaunchKernelGGL(k_cvt_w, dim3(256), dim3(256), 0, stream, wp, 256, WPH, WPL);
    hipLaunchKernelGGL(k_region_mean, dim3(512), dim3(256), 0, stream, x, XR);
    hipLaunchKernelGGL(k_region_qkv, dim3(512), dim3(256), 0, stream, XR, wqkv, bqkv, QKVR);
    hipLaunchKernelGGL(k_gating, dim3(512), dim3(64), 0, stream, QKVR, wg1, bg1, wg2, bg2, SIG);
    hipLaunchKernelGGL(k_topk_gauss, dim3(512), dim3(64), 0, stream, QKVR, SIG, TOPK, GWT);
    hipLaunchKernelGGL(k_mm_qkv, dim3(6, 196), dim3(256), 0, stream,
                       XH, XL, WQH, WQL, bqkv, Qp, Kp, Vp);
    hipLaunchKernelGGL(k_transpose_v, dim3(512), dim3(256), 0, stream, Vp, Vtp);
    hipLaunchKernelGGL(k_attn_logits2, dim3(512), dim3(256), 0, stream,
                       Qp, Kp, TOPK, GWT, Pp);
    hipLaunchKernelGGL(k_attn_pv2, dim3(512), dim3(256), 0, stream,
                       Pp, Vtp, TOPK, dwk, dwb, ATTp);
    hipLaunchKernelGGL(k_mm_proj, dim3(2, 196), dim3(256), 0, stream,
                       ATTp, WPH, WPL, bp, out);
}

// Round 8
// 374.873 us; speedup vs baseline: 1.9615x; 1.1633x over previous
//
#include <hip/hip_runtime.h>
#include <math.h>

#define SCALE 0.17677669529663687f  /* (256/8)^-0.5 */

typedef short short8 __attribute__((ext_vector_type(8)));
typedef float f32x4 __attribute__((ext_vector_type(4)));

// ---------------------------------------------------------------------------
__device__ __forceinline__ int token_row_addr(int m) {
    int b = m / 3136;
    int rem = m - b * 3136;
    int s = rem / 49;
    int tok = rem - s * 49;
    int h = (s >> 3) * 7 + tok / 7;
    int w = (s & 7) * 7 + (tok % 7);
    return (b * 56 + h) * 56 + w;
}

__device__ __forceinline__ void split2(float x, unsigned short& h, unsigned short& l) {
    unsigned int u = __float_as_uint(x);
    h = (unsigned short)(u >> 16);
    float hf = __uint_as_float(u & 0xFFFF0000u);
    l = (unsigned short)(__float_as_uint(x - hf) >> 16);
}

__device__ __forceinline__ unsigned int pack2(float x) {
    unsigned short h, l;
    split2(x, h, l);
    return ((unsigned int)h << 16) | l;
}

__device__ __forceinline__ float b2f(unsigned short u) {
    return __uint_as_float(((unsigned int)u) << 16);
}

__device__ __forceinline__ float unpack_f(unsigned int u) {
    return b2f((unsigned short)(u >> 16)) + b2f((unsigned short)(u & 0xFFFFu));
}

// unpack 8 packed u32 -> hi/lo bf16 fragments
__device__ __forceinline__ void unpack_u4(uint4 a, uint4 b, short8& h, short8& l) {
    h[0] = (short)(a.x >> 16); l[0] = (short)(a.x & 0xFFFFu);
    h[1] = (short)(a.y >> 16); l[1] = (short)(a.y & 0xFFFFu);
    h[2] = (short)(a.z >> 16); l[2] = (short)(a.z & 0xFFFFu);
    h[3] = (short)(a.w >> 16); l[3] = (short)(a.w & 0xFFFFu);
    h[4] = (short)(b.x >> 16); l[4] = (short)(b.x & 0xFFFFu);
    h[5] = (short)(b.y >> 16); l[5] = (short)(b.y & 0xFFFFu);
    h[6] = (short)(b.z >> 16); l[6] = (short)(b.z & 0xFFFFu);
    h[7] = (short)(b.w >> 16); l[7] = (short)(b.w & 0xFFFFu);
}

__device__ __forceinline__ void load_unpack8(const unsigned int* g, short8& h, short8& l) {
    uint4 a = *(const uint4*)g;
    uint4 b = *(const uint4*)(g + 4);
    unpack_u4(a, b, h, l);
}

// async global->LDS 16B per lane
__device__ __forceinline__ void gload16(const unsigned short* g, unsigned short* l) {
    __builtin_amdgcn_global_load_lds(
        (const __attribute__((address_space(1))) unsigned int*)g,
        (__attribute__((address_space(3))) unsigned int*)l, 16, 0, 0);
}

// ---------------------------------------------------------------------------
// converters
__global__ void k_cvt_x(const float* __restrict__ x, unsigned short* __restrict__ xhi,
                        unsigned short* __restrict__ xlo) {
    int m = blockIdx.x;
    int k = threadIdx.x;
    float v = x[(size_t)token_row_addr(m) * 256 + k];
    unsigned short h, l;
    split2(v, h, l);
    xhi[(size_t)m * 256 + k] = h;
    xlo[(size_t)m * 256 + k] = l;
}

__global__ void k_cvt_w(const float* __restrict__ w, int ncols,
                        unsigned short* __restrict__ whi, unsigned short* __restrict__ wlo) {
    int n = blockIdx.x;
    int k = threadIdx.x;
    float v = w[(size_t)k * ncols + n];
    unsigned short h, l;
    split2(v, h, l);
    whi[(size_t)n * 256 + k] = h;
    wlo[(size_t)n * 256 + k] = l;
}

// ---------------------------------------------------------------------------
// K0a..K0d: fp32 region path (unchanged)
__global__ void k_region_mean(const float* __restrict__ x, float* __restrict__ xr) {
    int blk = blockIdx.x;
    int b = blk >> 6, s = blk & 63;
    int c = threadIdx.x;
    int hy0 = (s >> 3) * 7, wx0 = (s & 7) * 7;
    const float* xb = x + ((size_t)b * 56 * 56) * 256 + c;
    float sum = 0.f;
#pragma unroll 1
    for (int t = 0; t < 49; ++t) {
        int h = hy0 + t / 7, w = wx0 + (t % 7);
        sum += xb[(size_t)(h * 56 + w) * 256];
    }
    xr[(size_t)blk * 256 + c] = sum * (1.0f / 49.0f);
}

__global__ void k_region_qkv(const float* __restrict__ xr, const float* __restrict__ wqkv,
                             const float* __restrict__ bqkv, float* __restrict__ qkvr) {
    __shared__ float xs[256];
    int blk = blockIdx.x;
    int t = threadIdx.x;
    xs[t] = xr[(size_t)blk * 256 + t];
    __syncthreads();
    float a0 = 0.f, a1 = 0.f, a2 = 0.f;
#pragma unroll 4
    for (int k = 0; k < 256; ++k) {
        float xv = xs[k];
        const float* wrow = wqkv + (size_t)k * 768;
        a0 += xv * wrow[t];
        a1 += xv * wrow[t + 256];
        a2 += xv * wrow[t + 512];
    }
    float* o = qkvr + (size_t)blk * 768;
    o[t]       = a0 + bqkv[t];
    o[t + 256] = a1 + bqkv[t + 256];
    o[t + 512] = a2 + bqkv[t + 512];
}

__global__ void k_gating(const float* __restrict__ qkvr, const float* __restrict__ wg1,
                         const float* __restrict__ bg1, const float* __restrict__ wg2,
                         const float* __restrict__ bg2, float* __restrict__ sig) {
    __shared__ float hs[64];
    int blk = blockIdx.x;
    int j = threadIdx.x;
    const float* qr = qkvr + (size_t)blk * 768;
    float acc = bg1[j];
#pragma unroll 4
    for (int k = 0; k < 256; ++k) acc += qr[k] * wg1[(size_t)k * 64 + j];
    hs[j] = fmaxf(acc, 0.f);
    __syncthreads();
    if (j < 2) {
        float gp = bg2[j];
#pragma unroll 1
        for (int m = 0; m < 64; ++m) gp += hs[m] * wg2[m * 2 + j];
        float sp = fmaxf(gp, 0.f) + log1pf(expf(-fabsf(gp)));
        sig[blk * 2 + j] = sp + 0.5f;
    }
}

__global__ void k_topk_gauss(const float* __restrict__ qkvr, const float* __restrict__ sig,
                             int* __restrict__ topk, float* __restrict__ gwt) {
    __shared__ float A[64];
    __shared__ float G[64];
    __shared__ int idxs[4];
    __shared__ float gsum_s;
    int blk = blockIdx.x;
    int b = blk >> 6, s = blk & 63;
    int z = threadIdx.x;
    const float* qr = qkvr + (size_t)blk * 768;
    const float* kr = qkvr + (size_t)(b * 64 + z) * 768 + 256;
    float acc = 0.f;
#pragma unroll 4
    for (int k = 0; k < 256; k += 4) {
        float4 q4 = *(const float4*)(qr + k);
        float4 k4 = *(const float4*)(kr + k);
        acc += q4.x * k4.x + q4.y * k4.y + q4.z * k4.z + q4.w * k4.w;
    }
    A[z] = acc * SCALE;
    float s0 = sig[blk * 2 + 0], s1 = sig[blk * 2 + 1];
    float dx = (float)((z & 7) - (s & 7));
    float dy = (float)((z >> 3) - (s >> 3));
    float t0 = dx / s0, t1 = dy / s1;
    float zz = t0 * t0 + t1 * t1;
    G[z] = expf(-0.5f * zz);
    __syncthreads();
    if (z == 0) {
        float gs = 0.f;
        for (int m = 0; m < 64; ++m) gs += G[m];
        gsum_s = gs + 1e-6f;
        for (int it = 0; it < 4; ++it) {
            int best = 0;
            float bv = A[0];
            for (int m = 1; m < 64; ++m) {
                if (A[m] > bv) { bv = A[m]; best = m; }
            }
            idxs[it] = best;
            A[best] = -3.0e38f;
        }
    }
    __syncthreads();
    if (z < 4) {
        int id = idxs[z];
        topk[blk * 4 + z] = id;
        gwt[blk * 4 + z] = G[id] / gsum_s;
    }
}

// ---------------------------------------------------------------------------
// K1: qkv GEMM, split-bf16 MFMA, 128x128 tile, BK=32. grid (6, 196).
__global__ __launch_bounds__(256) void k_mm_qkv(
    const unsigned short* __restrict__ xhi, const unsigned short* __restrict__ xlo,
    const unsigned short* __restrict__ whi, const unsigned short* __restrict__ wlo,
    const float* __restrict__ bqkv,
    unsigned int* __restrict__ Qp, unsigned int* __restrict__ Kp,
    unsigned int* __restrict__ Vp) {
    __shared__ __align__(16) unsigned short Ah[4096];
    __shared__ __align__(16) unsigned short Al[4096];
    __shared__ __align__(16) unsigned short Bh[4096];
    __shared__ __align__(16) unsigned short Bl[4096];
    int tid = threadIdx.x;
    int ln = tid & 63, wv = tid >> 6;
    int m0 = blockIdx.y * 128, n0 = blockIdx.x * 128;
    int mrow = (wv >> 1) * 64, ncol = (wv & 1) * 64;

    int lrow = ln >> 2, lseg = (ln & 3) * 8;
    const unsigned short* gA0 = xhi + (size_t)(m0 + wv * 32 + lrow) * 256 + lseg;
    const unsigned short* gA1 = gA0 + 16 * 256;
    const unsigned short* gAl0 = xlo + (size_t)(m0 + wv * 32 + lrow) * 256 + lseg;
    const unsigned short* gAl1 = gAl0 + 16 * 256;
    const unsigned short* gB0 = whi + (size_t)(n0 + wv * 32 + lrow) * 256 + lseg;
    const unsigned short* gB1 = gB0 + 16 * 256;
    const unsigned short* gBl0 = wlo + (size_t)(n0 + wv * 32 + lrow) * 256 + lseg;
    const unsigned short* gBl1 = gBl0 + 16 * 256;
    unsigned short* lA0 = &Ah[(wv * 32) * 32];
    unsigned short* lA1 = &Ah[(wv * 32 + 16) * 32];
    unsigned short* lAl0 = &Al[(wv * 32) * 32];
    unsigned short* lAl1 = &Al[(wv * 32 + 16) * 32];
    unsigned short* lB0 = &Bh[(wv * 32) * 32];
    unsigned short* lB1 = &Bh[(wv * 32 + 16) * 32];
    unsigned short* lBl0 = &Bl[(wv * 32) * 32];
    unsigned short* lBl1 = &Bl[(wv * 32 + 16) * 32];

    int fm = ln & 15, fq = (ln >> 4) * 8;
    f32x4 acc[4][4];
#pragma unroll
    for (int i = 0; i < 4; ++i)
#pragma unroll
        for (int j = 0; j < 4; ++j) acc[i][j] = (f32x4){0.f, 0.f, 0.f, 0.f};

#pragma unroll 1
    for (int kc = 0; kc < 8; ++kc) {
        if (kc) __syncthreads();
        gload16(gA0, lA0); gload16(gA1, lA1);
        gload16(gAl0, lAl0); gload16(gAl1, lAl1);
        gload16(gB0, lB0); gload16(gB1, lB1);
        gload16(gBl0, lBl0); gload16(gBl1, lBl1);
        gA0 += 32; gA1 += 32; gAl0 += 32; gAl1 += 32;
        gB0 += 32; gB1 += 32; gBl0 += 32; gBl1 += 32;
        __syncthreads();

        short8 ah[4], bh[4], xx[4];
#pragma unroll
        for (int mi = 0; mi < 4; ++mi)
            ah[mi] = *(const short8*)&Ah[(mrow + mi * 16 + fm) * 32 + fq];
#pragma unroll
        for (int ni = 0; ni < 4; ++ni)
            bh[ni] = *(const short8*)&Bh[(ncol + ni * 16 + fm) * 32 + fq];
#pragma unroll
        for (int mi = 0; mi < 4; ++mi)
#pragma unroll
            for (int ni = 0; ni < 4; ++ni)
                acc[mi][ni] = __builtin_amdgcn_mfma_f32_16x16x32_bf16(ah[mi], bh[ni], acc[mi][ni], 0, 0, 0);
#pragma unroll
        for (int mi = 0; mi < 4; ++mi)
            xx[mi] = *(const short8*)&Al[(mrow + mi * 16 + fm) * 32 + fq];
#pragma unroll
        for (int mi = 0; mi < 4; ++mi)
#pragma unroll
            for (int ni = 0; ni < 4; ++ni)
                acc[mi][ni] = __builtin_amdgcn_mfma_f32_16x16x32_bf16(xx[mi], bh[ni], acc[mi][ni], 0, 0, 0);
#pragma unroll
        for (int ni = 0; ni < 4; ++ni)
            xx[ni] = *(const short8*)&Bl[(ncol + ni * 16 + fm) * 32 + fq];
#pragma unroll
        for (int mi = 0; mi < 4; ++mi)
#pragma unroll
            for (int ni = 0; ni < 4; ++ni)
                acc[mi][ni] = __builtin_amdgcn_mfma_f32_16x16x32_bf16(ah[mi], xx[ni], acc[mi][ni], 0, 0, 0);
    }

    int nb = n0 >> 7;  // 0,1->Q  2,3->K  4,5->V
    unsigned int* dst = (nb < 2) ? Qp : (nb < 4) ? Kp : Vp;
    int qrow = (ln >> 4) * 4;
#pragma unroll
    for (int ni = 0; ni < 4; ++ni) {
        int col = (n0 & 255) + ncol + ni * 16 + fm;
        float bias = bqkv[n0 + ncol + ni * 16 + fm];
#pragma unroll
        for (int mi = 0; mi < 4; ++mi) {
#pragma unroll
            for (int r = 0; r < 4; ++r) {
                int m = m0 + mrow + mi * 16 + qrow + r;
                dst[(size_t)m * 256 + col] = pack2(acc[mi][ni][r] + bias);
            }
        }
    }
}

// ---------------------------------------------------------------------------
// K1b: transpose Vp [win*49+tok][256] -> Vtp[win][c][64] packed, pads zeroed.
__global__ __launch_bounds__(256) void k_transpose_v(
    const unsigned int* __restrict__ Vp, unsigned int* __restrict__ Vtp) {
    __shared__ unsigned int T[49][257];
    int win = blockIdx.x;
    int tid = threadIdx.x;
#pragma unroll 1
    for (int i = tid; i < 49 * 64; i += 256) {
        int tok = i >> 6, cq = (i & 63) * 4;
        uint4 v = *(const uint4*)&Vp[((size_t)win * 49 + tok) * 256 + cq];
        T[tok][cq + 0] = v.x;
        T[tok][cq + 1] = v.y;
        T[tok][cq + 2] = v.z;
        T[tok][cq + 3] = v.w;
    }
    __syncthreads();
#pragma unroll 1
    for (int it = 0; it < 8; ++it) {
        int item = tid + it * 256;
        int c = item >> 3, t8 = (item & 7) * 8;
        uint4 o0, o1;
        o0.x = (t8 + 0 < 49) ? T[t8 + 0][c] : 0u;
        o0.y = (t8 + 1 < 49) ? T[t8 + 1][c] : 0u;
        o0.z = (t8 + 2 < 49) ? T[t8 + 2][c] : 0u;
        o0.w = (t8 + 3 < 49) ? T[t8 + 3][c] : 0u;
        o1.x = (t8 + 4 < 49) ? T[t8 + 4][c] : 0u;
        o1.y = (t8 + 5 < 49) ? T[t8 + 5][c] : 0u;
        o1.z = (t8 + 6 < 49) ? T[t8 + 6][c] : 0u;
        o1.w = (t8 + 7 < 49) ? T[t8 + 7][c] : 0u;
        size_t o = (size_t)win * 16384 + (size_t)c * 64 + t8;
        *(uint4*)&Vtp[o] = o0;
        *(uint4*)&Vtp[o + 4] = o1;
    }
}

// ---------------------------------------------------------------------------
// K2a: QK^T (3-pass MFMA from packed Q/K) + register softmax + packed P store.
// grid 512 (XCD-swizzled: blk%8 = batch), block 256 (wave = region).
__global__ __launch_bounds__(256) void k_attn_logits2(
    const unsigned int* __restrict__ Qp, const unsigned int* __restrict__ Kp,
    const int* __restrict__ topk, const float* __restrict__ gwt,
    unsigned int* __restrict__ Pp) {
    __shared__ float redm[4][64];
    __shared__ float reds[4][64];
    __shared__ float gmax[64];
    __shared__ float ginv[64];
    int blk = blockIdx.x;
    int win = ((blk & 7) << 6) | (blk >> 3);  // batch-per-XCD affinity
    int b = win >> 6;
    int tid = threadIdx.x, ln = tid & 63, wv = tid >> 6;
    int fm = ln & 15, g = ln >> 4, fq = g * 8;

    int myreg = topk[win * 4 + wv];
    float gw = gwt[win * 4 + wv];
    float sg = SCALE * gw;
    size_t qbase = (size_t)win * 49 * 256;
    size_t kbase = (size_t)(b * 64 + myreg) * 49 * 256;

    f32x4 acc[4][4];
#pragma unroll
    for (int i = 0; i < 4; ++i)
#pragma unroll
        for (int j = 0; j < 4; ++j) acc[i][j] = (f32x4){0.f, 0.f, 0.f, 0.f};

#pragma unroll 1
    for (int kc = 0; kc < 256; kc += 32) {
        short8 ah[4], al[4], bh[4], bl[4];
#pragma unroll
        for (int mi = 0; mi < 4; ++mi)
            load_unpack8(&Qp[qbase + (size_t)(mi * 16 + fm) * 256 + kc + fq], ah[mi], al[mi]);
#pragma unroll
        for (int ni = 0; ni < 4; ++ni)
            load_unpack8(&Kp[kbase + (size_t)(ni * 16 + fm) * 256 + kc + fq], bh[ni], bl[ni]);
#pragma unroll
        for (int mi = 0; mi < 4; ++mi)
#pragma unroll
            for (int ni = 0; ni < 4; ++ni) {
                acc[mi][ni] = __builtin_amdgcn_mfma_f32_16x16x32_bf16(ah[mi], bh[ni], acc[mi][ni], 0, 0, 0);
                acc[mi][ni] = __builtin_amdgcn_mfma_f32_16x16x32_bf16(al[mi], bh[ni], acc[mi][ni], 0, 0, 0);
                acc[mi][ni] = __builtin_amdgcn_mfma_f32_16x16x32_bf16(ah[mi], bl[ni], acc[mi][ni], 0, 0, 0);
            }
    }

#pragma unroll
    for (int mi = 0; mi < 4; ++mi)
#pragma unroll
        for (int ni = 0; ni < 4; ++ni) acc[mi][ni] *= sg;

    float rmax[4][4];
#pragma unroll
    for (int mi = 0; mi < 4; ++mi)
#pragma unroll
        for (int r = 0; r < 4; ++r) rmax[mi][r] = -3.0e38f;
#pragma unroll
    for (int mi = 0; mi < 4; ++mi)
#pragma unroll
        for (int ni = 0; ni < 4; ++ni) {
            if (ni * 16 + fm < 49) {
#pragma unroll
                for (int r = 0; r < 4; ++r)
                    rmax[mi][r] = fmaxf(rmax[mi][r], acc[mi][ni][r]);
            }
        }
#pragma unroll
    for (int off = 1; off < 16; off <<= 1)
#pragma unroll
        for (int mi = 0; mi < 4; ++mi)
#pragma unroll
            for (int r = 0; r < 4; ++r)
                rmax[mi][r] = fmaxf(rmax[mi][r], __shfl_xor(rmax[mi][r], off, 64));
    if (fm == 0) {
#pragma unroll
        for (int mi = 0; mi < 4; ++mi)
#pragma unroll
            for (int r = 0; r < 4; ++r)
                redm[wv][mi * 16 + g * 4 + r] = rmax[mi][r];
    }
    __syncthreads();
    if (tid < 64)
        gmax[tid] = fmaxf(fmaxf(redm[0][tid], redm[1][tid]),
                          fmaxf(redm[2][tid], redm[3][tid]));
    __syncthreads();

    float gm[4][4];
#pragma unroll
    for (int mi = 0; mi < 4; ++mi)
#pragma unroll
        for (int r = 0; r < 4; ++r) gm[mi][r] = gmax[mi * 16 + g * 4 + r];
    float rsum[4][4];
#pragma unroll
    for (int mi = 0; mi < 4; ++mi)
#pragma unroll
        for (int r = 0; r < 4; ++r) rsum[mi][r] = 0.f;
#pragma unroll
    for (int mi = 0; mi < 4; ++mi)
#pragma unroll
        for (int ni = 0; ni < 4; ++ni) {
            bool valid = (ni * 16 + fm) < 49;
#pragma unroll
            for (int r = 0; r < 4; ++r) {
                float e = valid ? __expf(acc[mi][ni][r] - gm[mi][r]) : 0.f;
                acc[mi][ni][r] = e;
                rsum[mi][r] += e;
            }
        }
#pragma unroll
    for (int off = 1; off < 16; off <<= 1)
#pragma unroll
        for (int mi = 0; mi < 4; ++mi)
#pragma unroll
            for (int r = 0; r < 4; ++r)
                rsum[mi][r] += __shfl_xor(rsum[mi][r], off, 64);
    if (fm == 0) {
#pragma unroll
        for (int mi = 0; mi < 4; ++mi)
#pragma unroll
            for (int r = 0; r < 4; ++r)
                reds[wv][mi * 16 + g * 4 + r] = rsum[mi][r];
    }
    __syncthreads();
    if (tid < 64)
        ginv[tid] = 1.0f / (reds[0][tid] + reds[1][tid] + reds[2][tid] + reds[3][tid]);
    __syncthreads();

    size_t pbase = (size_t)win * 16384 + wv * 64;
#pragma unroll
    for (int mi = 0; mi < 4; ++mi) {
#pragma unroll
        for (int r = 0; r < 4; ++r) {
            int row = mi * 16 + g * 4 + r;
            float giv = (row < 49) ? ginv[row] * gw : 0.f;
#pragma unroll
            for (int ni = 0; ni < 4; ++ni) {
                float p = acc[mi][ni][r] * giv;
                Pp[pbase + (size_t)row * 256 + ni * 16 + fm] = pack2(p);
            }
        }
    }
}

// ---------------------------------------------------------------------------
// K2b: PV (3-pass MFMA from packed P/Vt) + fused dwconv (own-window V staged
// in LDS -- kills the 16-way segment gathers). grid 512 (XCD-swizzled).
__global__ __launch_bounds__(256) void k_attn_pv2(
    const unsigned int* __restrict__ Pp, const unsigned int* __restrict__ Vtp,
    const unsigned int* __restrict__ Vp,
    const int* __restrict__ topk, const float* __restrict__ dwk,
    const float* __restrict__ dwb, unsigned int* __restrict__ ATTp) {
    __shared__ unsigned int Vs[49][258];  // own-window V, tok-major, padded
    int blk = blockIdx.x;
    int win = ((blk & 7) << 6) | (blk >> 3);  // batch-per-XCD affinity
    int b = win >> 6;
    int tid = threadIdx.x, ln = tid & 63, wv = tid >> 6;
    int fm = ln & 15, g = ln >> 4, fq = g * 8;
    int ncol = wv * 64;
    size_t pbase = (size_t)win * 16384;

    // stage own-window V for dwconv (coalesced uint4 loads)
#pragma unroll 1
    for (int i = tid; i < 49 * 64; i += 256) {
        int tok = i >> 6, cq = (i & 63) * 4;
        uint4 v = *(const uint4*)&Vp[((size_t)win * 49 + tok) * 256 + cq];
        Vs[tok][cq + 0] = v.x;
        Vs[tok][cq + 1] = v.y;
        Vs[tok][cq + 2] = v.z;
        Vs[tok][cq + 3] = v.w;
    }
    __syncthreads();

    f32x4 oacc[4][4];
#pragma unroll
    for (int i = 0; i < 4; ++i)
#pragma unroll
        for (int j = 0; j < 4; ++j) oacc[i][j] = (f32x4){0.f, 0.f, 0.f, 0.f};

#pragma unroll 1
    for (int r = 0; r < 4; ++r) {
        int reg = topk[win * 4 + r];
        size_t vbase = (size_t)(b * 64 + reg) * 16384;
#pragma unroll
        for (int half = 0; half < 2; ++half) {
            int kc = r * 64 + half * 32;
            int tokoff = half * 32;
            short8 ah[4], al[4], bh[4], bl[4];
#pragma unroll
            for (int mi = 0; mi < 4; ++mi)
                load_unpack8(&Pp[pbase + (size_t)(mi * 16 + fm) * 256 + kc + fq], ah[mi], al[mi]);
#pragma unroll
            for (int ni = 0; ni < 4; ++ni)
                load_unpack8(&Vtp[vbase + (size_t)(ncol + ni * 16 + fm) * 64 + tokoff + fq], bh[ni], bl[ni]);
#pragma unroll
            for (int mi = 0; mi < 4; ++mi)
#pragma unroll
                for (int ni = 0; ni < 4; ++ni) {
                    oacc[mi][ni] = __builtin_amdgcn_mfma_f32_16x16x32_bf16(ah[mi], bh[ni], oacc[mi][ni], 0, 0, 0);
                    oacc[mi][ni] = __builtin_amdgcn_mfma_f32_16x16x32_bf16(al[mi], bh[ni], oacc[mi][ni], 0, 0, 0);
                    oacc[mi][ni] = __builtin_amdgcn_mfma_f32_16x16x32_bf16(ah[mi], bl[ni], oacc[mi][ni], 0, 0, 0);
                }
        }
    }

    // epilogue: dwconv reads LDS Vs + packed store
#pragma unroll 1
    for (int ni = 0; ni < 4; ++ni) {
        int c = ncol + ni * 16 + fm;
        float dk[9];
#pragma unroll
        for (int t = 0; t < 9; ++t) dk[t] = dwk[(size_t)t * 256 + c];
        float db = dwb[c];
#pragma unroll
        for (int mi = 0; mi < 4; ++mi) {
#pragma unroll
            for (int rr = 0; rr < 4; ++rr) {
                int w = mi * 16 + g * 4 + rr;
                if (w < 49) {
                    int py = w / 7, px = w - py * 7;
                    float vd = db;
#pragma unroll
                    for (int dy = 0; dy < 3; ++dy) {
                        int yy = py + dy - 1;
                        if (yy < 0 || yy > 6) continue;
#pragma unroll
                        for (int dx = 0; dx < 3; ++dx) {
                            int xx = px + dx - 1;
                            if (xx < 0 || xx > 6) continue;
                            vd += unpack_f(Vs[yy * 7 + xx][c]) * dk[dy * 3 + dx];
                        }
                    }
                    ATTp[((size_t)win * 49 + w) * 256 + c] = pack2(oacc[mi][ni][rr] + vd);
                }
            }
        }
    }
}

// ---------------------------------------------------------------------------
// K3: proj GEMM, split-bf16 MFMA. A = packed ATT staged into padded LDS.
__global__ __launch_bounds__(256) void k_mm_proj(
    const unsigned int* __restrict__ Ap,
    const unsigned short* __restrict__ whi, const unsigned short* __restrict__ wlo,
    const float* __restrict__ bp, float* __restrict__ out) {
    __shared__ __align__(16) unsigned int As[128 * 36];
    __shared__ __align__(16) unsigned short Bh[4096];
    __shared__ __align__(16) unsigned short Bl[4096];
    int tid = threadIdx.x;
    int ln = tid & 63, wv = tid >> 6;
    int m0 = blockIdx.y * 128, n0 = blockIdx.x * 128;
    int mrow = (wv >> 1) * 64, ncol = (wv & 1) * 64;

    int lrow = ln >> 2, lseg = (ln & 3) * 8;
    const unsigned short* gB0 = whi + (size_t)(n0 + wv * 32 + lrow) * 256 + lseg;
    const unsigned short* gB1 = gB0 + 16 * 256;
    const unsigned short* gBl0 = wlo + (size_t)(n0 + wv * 32 + lrow) * 256 + lseg;
    const unsigned short* gBl1 = gBl0 + 16 * 256;
    unsigned short* lB0 = &Bh[(wv * 32) * 32];
    unsigned short* lB1 = &Bh[(wv * 32 + 16) * 32];
    unsigned short* lBl0 = &Bl[(wv * 32) * 32];
    unsigned short* lBl1 = &Bl[(wv * 32 + 16) * 32];

    int arow = ln >> 3, akk = (ln & 7) * 4;
    int fm = ln & 15, fq = (ln >> 4) * 8;
    f32x4 acc[4][4];
#pragma unroll
    for (int i = 0; i < 4; ++i)
#pragma unroll
        for (int j = 0; j < 4; ++j) acc[i][j] = (f32x4){0.f, 0.f, 0.f, 0.f};

#pragma unroll 1
    for (int kc = 0; kc < 8; ++kc) {
        if (kc) __syncthreads();
        gload16(gB0, lB0); gload16(gB1, lB1);
        gload16(gBl0, lBl0); gload16(gBl1, lBl1);
        gB0 += 32; gB1 += 32; gBl0 += 32; gBl1 += 32;
#pragma unroll
        for (int it = 0; it < 4; ++it) {
            int row = wv * 32 + it * 8 + arow;
            uint4 v = *(const uint4*)&Ap[(size_t)(m0 + row) * 256 + kc * 32 + akk];
            *(uint4*)&As[row * 36 + akk] = v;
        }
        __syncthreads();

        short8 ah[4], al[4], bh[4], xx[4];
#pragma unroll
        for (int mi = 0; mi < 4; ++mi) {
            const unsigned int* p = &As[(mrow + mi * 16 + fm) * 36 + fq];
            unpack_u4(*(const uint4*)p, *(const uint4*)(p + 4), ah[mi], al[mi]);
        }
#pragma unroll
        for (int ni = 0; ni < 4; ++ni)
            bh[ni] = *(const short8*)&Bh[(ncol + ni * 16 + fm) * 32 + fq];
#pragma unroll
        for (int mi = 0; mi < 4; ++mi)
#pragma unroll
            for (int ni = 0; ni < 4; ++ni)
                acc[mi][ni] = __builtin_amdgcn_mfma_f32_16x16x32_bf16(ah[mi], bh[ni], acc[mi][ni], 0, 0, 0);
#pragma unroll
        for (int mi = 0; mi < 4; ++mi)
#pragma unroll
            for (int ni = 0; ni < 4; ++ni)
                acc[mi][ni] = __builtin_amdgcn_mfma_f32_16x16x32_bf16(al[mi], bh[ni], acc[mi][ni], 0, 0, 0);
#pragma unroll
        for (int ni = 0; ni < 4; ++ni)
            xx[ni] = *(const short8*)&Bl[(ncol + ni * 16 + fm) * 32 + fq];
#pragma unroll
        for (int mi = 0; mi < 4; ++mi)
#pragma unroll
            for (int ni = 0; ni < 4; ++ni)
                acc[mi][ni] = __builtin_amdgcn_mfma_f32_16x16x32_bf16(ah[mi], xx[ni], acc[mi][ni], 0, 0, 0);
    }

    int qrow = (ln >> 4) * 4;
#pragma unroll
    for (int mi = 0; mi < 4; ++mi) {
#pragma unroll
        for (int r = 0; r < 4; ++r) {
            int m = m0 + mrow + mi * 16 + qrow + r;
            size_t orow = (size_t)token_row_addr(m);
#pragma unroll
            for (int ni = 0; ni < 4; ++ni) {
                int col = n0 + ncol + ni * 16 + fm;
                out[orow * 256 + col] = acc[mi][ni][r] + bp[col];
            }
        }
    }
}

// ---------------------------------------------------------------------------
extern "C" void kernel_launch(void* const* d_in, const int* in_sizes, int n_in,
                              void* d_out, int out_size, void* d_ws, size_t ws_size,
                              hipStream_t stream) {
    const float* x    = (const float*)d_in[0];
    const float* wqkv = (const float*)d_in[1];
    const float* bqkv = (const float*)d_in[2];
    const float* wg1  = (const float*)d_in[3];
    const float* bg1  = (const float*)d_in[4];
    const float* wg2  = (const float*)d_in[5];
    const float* bg2  = (const float*)d_in[6];
    const float* dwk  = (const float*)d_in[7];
    const float* dwb  = (const float*)d_in[8];
    const float* wp   = (const float*)d_in[9];
    const float* bp   = (const float*)d_in[10];
    float* out = (float*)d_out;

    const size_t NTOT = (size_t)25088 * 256;     // 6,422,528
    const size_t VTSZ = (size_t)512 * 256 * 64;  // 8,388,608
    unsigned int* Qp  = (unsigned int*)d_ws;
    unsigned int* Kp  = Qp + NTOT;
    unsigned int* Vp  = Kp + NTOT;
    unsigned int* Vtp = Vp + NTOT;
    unsigned int* Pp  = Vtp + VTSZ;
    unsigned short* XH = (unsigned short*)(Pp + VTSZ);  // x bf16 hi; later ATTp
    unsigned short* XL = XH + NTOT;                     // x bf16 lo
    unsigned int* ATTp = (unsigned int*)XH;             // alias (x dead after qkv)
    unsigned short* WQH = XL + NTOT;
    unsigned short* WQL = WQH + 768 * 256;
    unsigned short* WPH = WQL + 768 * 256;
    unsigned short* WPL = WPH + 256 * 256;
    float* XR   = (float*)(WPL + 256 * 256);
    float* QKVR = XR + 512 * 256;
    float* SIG  = QKVR + 512 * 768;
    float* GWT  = SIG + 1024;
    int*   TOPK = (int*)(GWT + 2048);

    hipLaunchKernelGGL(k_cvt_x, dim3(25088), dim3(256), 0, stream, x, XH, XL);
    hipLaunchKernelGGL(k_cvt_w, dim3(768), dim3(256), 0, stream, wqkv, 768, WQH, WQL);
    hipLaunchKernelGGL(k_cvt_w, dim3(256), dim3(256), 0, stream, wp, 256, WPH, WPL);
    hipLaunchKernelGGL(k_region_mean, dim3(512), dim3(256), 0, stream, x, XR);
    hipLaunchKernelGGL(k_region_qkv, dim3(512), dim3(256), 0, stream, XR, wqkv, bqkv, QKVR);
    hipLaunchKernelGGL(k_gating, dim3(512), dim3(64), 0, stream, QKVR, wg1, bg1, wg2, bg2, SIG);
    hipLaunchKernelGGL(k_topk_gauss, dim3(512), dim3(64), 0, stream, QKVR, SIG, TOPK, GWT);
    hipLaunchKernelGGL(k_mm_qkv, dim3(6, 196), dim3(256), 0, stream,
                       XH, XL, WQH, WQL, bqkv, Qp, Kp, Vp);
    hipLaunchKernelGGL(k_transpose_v, dim3(512), dim3(256), 0, stream, Vp, Vtp);
    hipLaunchKernelGGL(k_attn_logits2, dim3(512), dim3(256), 0, stream,
                       Qp, Kp, TOPK, GWT, Pp);
    hipLaunchKernelGGL(k_attn_pv2, dim3(512), dim3(256), 0, stream,
                       Pp, Vtp, Vp, TOPK, dwk, dwb, ATTp);
    hipLaunchKernelGGL(k_mm_proj, dim3(2, 196), dim3(256), 0, stream,
                       ATTp, WPH, WPL, bp, out);
}

// Round 9
// 366.024 us; speedup vs baseline: 2.0089x; 1.0242x over previous
//
#include <hip/hip_runtime.h>
#include <math.h>

#define SCALE 0.17677669529663687f  /* (256/8)^-0.5 */

typedef short short8 __attribute__((ext_vector_type(8)));
typedef float f32x4 __attribute__((ext_vector_type(4)));

// ---------------------------------------------------------------------------
__device__ __forceinline__ int token_row_addr(int m) {
    int b = m / 3136;
    int rem = m - b * 3136;
    int s = rem / 49;
    int tok = rem - s * 49;
    int h = (s >> 3) * 7 + tok / 7;
    int w = (s & 7) * 7 + (tok % 7);
    return (b * 56 + h) * 56 + w;
}

__device__ __forceinline__ void split2(float x, unsigned short& h, unsigned short& l) {
    unsigned int u = __float_as_uint(x);
    h = (unsigned short)(u >> 16);
    float hf = __uint_as_float(u & 0xFFFF0000u);
    l = (unsigned short)(__float_as_uint(x - hf) >> 16);
}

__device__ __forceinline__ unsigned int pack2(float x) {
    unsigned short h, l;
    split2(x, h, l);
    return ((unsigned int)h << 16) | l;
}

__device__ __forceinline__ float b2f(unsigned short u) {
    return __uint_as_float(((unsigned int)u) << 16);
}

__device__ __forceinline__ float unpack_f(unsigned int u) {
    return b2f((unsigned short)(u >> 16)) + b2f((unsigned short)(u & 0xFFFFu));
}

__device__ __forceinline__ void unpack_u4(uint4 a, uint4 b, short8& h, short8& l) {
    h[0] = (short)(a.x >> 16); l[0] = (short)(a.x & 0xFFFFu);
    h[1] = (short)(a.y >> 16); l[1] = (short)(a.y & 0xFFFFu);
    h[2] = (short)(a.z >> 16); l[2] = (short)(a.z & 0xFFFFu);
    h[3] = (short)(a.w >> 16); l[3] = (short)(a.w & 0xFFFFu);
    h[4] = (short)(b.x >> 16); l[4] = (short)(b.x & 0xFFFFu);
    h[5] = (short)(b.y >> 16); l[5] = (short)(b.y & 0xFFFFu);
    h[6] = (short)(b.z >> 16); l[6] = (short)(b.z & 0xFFFFu);
    h[7] = (short)(b.w >> 16); l[7] = (short)(b.w & 0xFFFFu);
}

__device__ __forceinline__ void load_unpack8(const unsigned int* g, short8& h, short8& l) {
    uint4 a = *(const uint4*)g;
    uint4 b = *(const uint4*)(g + 4);
    unpack_u4(a, b, h, l);
}

__device__ __forceinline__ void gload16(const unsigned short* g, unsigned short* l) {
    __builtin_amdgcn_global_load_lds(
        (const __attribute__((address_space(1))) unsigned int*)g,
        (__attribute__((address_space(3))) unsigned int*)l, 16, 0, 0);
}

// ---------------------------------------------------------------------------
// converters
__global__ void k_cvt_x(const float* __restrict__ x, unsigned short* __restrict__ xhi,
                        unsigned short* __restrict__ xlo) {
    int m = blockIdx.x;
    int k = threadIdx.x;
    float v = x[(size_t)token_row_addr(m) * 256 + k];
    unsigned short h, l;
    split2(v, h, l);
    xhi[(size_t)m * 256 + k] = h;
    xlo[(size_t)m * 256 + k] = l;
}

__global__ void k_cvt_w(const float* __restrict__ w, int ncols,
                        unsigned short* __restrict__ whi, unsigned short* __restrict__ wlo) {
    int n = blockIdx.x;
    int k = threadIdx.x;
    float v = w[(size_t)k * ncols + n];
    unsigned short h, l;
    split2(v, h, l);
    whi[(size_t)n * 256 + k] = h;
    wlo[(size_t)n * 256 + k] = l;
}

// ---------------------------------------------------------------------------
// K0: fused region path: mean -> qkv_r -> gating. grid 512, block 256.
__global__ void k_region_fused(const float* __restrict__ x, const float* __restrict__ wqkv,
                               const float* __restrict__ bqkv, const float* __restrict__ wg1,
                               const float* __restrict__ bg1, const float* __restrict__ wg2,
                               const float* __restrict__ bg2, float* __restrict__ qkvr,
                               float* __restrict__ sig) {
    __shared__ float xs[256];
    __shared__ float qbuf[256];
    __shared__ float hs[64];
    int blk = blockIdx.x;
    int b = blk >> 6, s = blk & 63;
    int t = threadIdx.x;
    int hy0 = (s >> 3) * 7, wx0 = (s & 7) * 7;
    const float* xb = x + ((size_t)b * 56 * 56) * 256 + t;
    float sum = 0.f;
#pragma unroll 1
    for (int tt = 0; tt < 49; ++tt) {
        int h = hy0 + tt / 7, w = wx0 + (tt % 7);
        sum += xb[(size_t)(h * 56 + w) * 256];
    }
    xs[t] = sum * (1.0f / 49.0f);
    __syncthreads();

    float a0 = 0.f, a1 = 0.f, a2 = 0.f;
#pragma unroll 4
    for (int k = 0; k < 256; ++k) {
        float xv = xs[k];
        const float* wrow = wqkv + (size_t)k * 768;
        a0 += xv * wrow[t];
        a1 += xv * wrow[t + 256];
        a2 += xv * wrow[t + 512];
    }
    float q = a0 + bqkv[t];
    qbuf[t] = q;
    float* o = qkvr + (size_t)blk * 768;
    o[t]       = q;
    o[t + 256] = a1 + bqkv[t + 256];
    o[t + 512] = a2 + bqkv[t + 512];
    __syncthreads();

    if (t < 64) {
        float acc = bg1[t];
#pragma unroll 4
        for (int k = 0; k < 256; ++k) acc += qbuf[k] * wg1[(size_t)k * 64 + t];
        hs[t] = fmaxf(acc, 0.f);
    }
    __syncthreads();
    if (t < 2) {
        float gp = bg2[t];
#pragma unroll 1
        for (int m = 0; m < 64; ++m) gp += hs[m] * wg2[m * 2 + t];
        float sp = fmaxf(gp, 0.f) + log1pf(expf(-fabsf(gp)));
        sig[blk * 2 + t] = sp + 0.5f;
    }
}

__global__ void k_topk_gauss(const float* __restrict__ qkvr, const float* __restrict__ sig,
                             int* __restrict__ topk, float* __restrict__ gwt) {
    __shared__ float A[64];
    __shared__ float G[64];
    __shared__ int idxs[4];
    __shared__ float gsum_s;
    int blk = blockIdx.x;
    int b = blk >> 6, s = blk & 63;
    int z = threadIdx.x;
    const float* qr = qkvr + (size_t)blk * 768;
    const float* kr = qkvr + (size_t)(b * 64 + z) * 768 + 256;
    float acc = 0.f;
#pragma unroll 4
    for (int k = 0; k < 256; k += 4) {
        float4 q4 = *(const float4*)(qr + k);
        float4 k4 = *(const float4*)(kr + k);
        acc += q4.x * k4.x + q4.y * k4.y + q4.z * k4.z + q4.w * k4.w;
    }
    A[z] = acc * SCALE;
    float s0 = sig[blk * 2 + 0], s1 = sig[blk * 2 + 1];
    float dx = (float)((z & 7) - (s & 7));
    float dy = (float)((z >> 3) - (s >> 3));
    float t0 = dx / s0, t1 = dy / s1;
    float zz = t0 * t0 + t1 * t1;
    G[z] = expf(-0.5f * zz);
    __syncthreads();
    if (z == 0) {
        float gs = 0.f;
        for (int m = 0; m < 64; ++m) gs += G[m];
        gsum_s = gs + 1e-6f;
        for (int it = 0; it < 4; ++it) {
            int best = 0;
            float bv = A[0];
            for (int m = 1; m < 64; ++m) {
                if (A[m] > bv) { bv = A[m]; best = m; }
            }
            idxs[it] = best;
            A[best] = -3.0e38f;
        }
    }
    __syncthreads();
    if (z < 4) {
        int id = idxs[z];
        topk[blk * 4 + z] = id;
        gwt[blk * 4 + z] = G[id] / gsum_s;
    }
}

// ---------------------------------------------------------------------------
// K1: qkv GEMM, split-bf16 MFMA, 128x128 tile, BK=32. grid (6, 196).
__global__ __launch_bounds__(256) void k_mm_qkv(
    const unsigned short* __restrict__ xhi, const unsigned short* __restrict__ xlo,
    const unsigned short* __restrict__ whi, const unsigned short* __restrict__ wlo,
    const float* __restrict__ bqkv,
    unsigned int* __restrict__ Qp, unsigned int* __restrict__ Kp,
    unsigned int* __restrict__ Vp) {
    __shared__ __align__(16) unsigned short Ah[4096];
    __shared__ __align__(16) unsigned short Al[4096];
    __shared__ __align__(16) unsigned short Bh[4096];
    __shared__ __align__(16) unsigned short Bl[4096];
    int tid = threadIdx.x;
    int ln = tid & 63, wv = tid >> 6;
    int m0 = blockIdx.y * 128, n0 = blockIdx.x * 128;
    int mrow = (wv >> 1) * 64, ncol = (wv & 1) * 64;

    int lrow = ln >> 2, lseg = (ln & 3) * 8;
    const unsigned short* gA0 = xhi + (size_t)(m0 + wv * 32 + lrow) * 256 + lseg;
    const unsigned short* gA1 = gA0 + 16 * 256;
    const unsigned short* gAl0 = xlo + (size_t)(m0 + wv * 32 + lrow) * 256 + lseg;
    const unsigned short* gAl1 = gAl0 + 16 * 256;
    const unsigned short* gB0 = whi + (size_t)(n0 + wv * 32 + lrow) * 256 + lseg;
    const unsigned short* gB1 = gB0 + 16 * 256;
    const unsigned short* gBl0 = wlo + (size_t)(n0 + wv * 32 + lrow) * 256 + lseg;
    const unsigned short* gBl1 = gBl0 + 16 * 256;
    unsigned short* lA0 = &Ah[(wv * 32) * 32];
    unsigned short* lA1 = &Ah[(wv * 32 + 16) * 32];
    unsigned short* lAl0 = &Al[(wv * 32) * 32];
    unsigned short* lAl1 = &Al[(wv * 32 + 16) * 32];
    unsigned short* lB0 = &Bh[(wv * 32) * 32];
    unsigned short* lB1 = &Bh[(wv * 32 + 16) * 32];
    unsigned short* lBl0 = &Bl[(wv * 32) * 32];
    unsigned short* lBl1 = &Bl[(wv * 32 + 16) * 32];

    int fm = ln & 15, fq = (ln >> 4) * 8;
    f32x4 acc[4][4];
#pragma unroll
    for (int i = 0; i < 4; ++i)
#pragma unroll
        for (int j = 0; j < 4; ++j) acc[i][j] = (f32x4){0.f, 0.f, 0.f, 0.f};

#pragma unroll 1
    for (int kc = 0; kc < 8; ++kc) {
        if (kc) __syncthreads();
        gload16(gA0, lA0); gload16(gA1, lA1);
        gload16(gAl0, lAl0); gload16(gAl1, lAl1);
        gload16(gB0, lB0); gload16(gB1, lB1);
        gload16(gBl0, lBl0); gload16(gBl1, lBl1);
        gA0 += 32; gA1 += 32; gAl0 += 32; gAl1 += 32;
        gB0 += 32; gB1 += 32; gBl0 += 32; gBl1 += 32;
        __syncthreads();

        short8 ah[4], bh[4], xx[4];
#pragma unroll
        for (int mi = 0; mi < 4; ++mi)
            ah[mi] = *(const short8*)&Ah[(mrow + mi * 16 + fm) * 32 + fq];
#pragma unroll
        for (int ni = 0; ni < 4; ++ni)
            bh[ni] = *(const short8*)&Bh[(ncol + ni * 16 + fm) * 32 + fq];
#pragma unroll
        for (int mi = 0; mi < 4; ++mi)
#pragma unroll
            for (int ni = 0; ni < 4; ++ni)
                acc[mi][ni] = __builtin_amdgcn_mfma_f32_16x16x32_bf16(ah[mi], bh[ni], acc[mi][ni], 0, 0, 0);
#pragma unroll
        for (int mi = 0; mi < 4; ++mi)
            xx[mi] = *(const short8*)&Al[(mrow + mi * 16 + fm) * 32 + fq];
#pragma unroll
        for (int mi = 0; mi < 4; ++mi)
#pragma unroll
            for (int ni = 0; ni < 4; ++ni)
                acc[mi][ni] = __builtin_amdgcn_mfma_f32_16x16x32_bf16(xx[mi], bh[ni], acc[mi][ni], 0, 0, 0);
#pragma unroll
        for (int ni = 0; ni < 4; ++ni)
            xx[ni] = *(const short8*)&Bl[(ncol + ni * 16 + fm) * 32 + fq];
#pragma unroll
        for (int mi = 0; mi < 4; ++mi)
#pragma unroll
            for (int ni = 0; ni < 4; ++ni)
                acc[mi][ni] = __builtin_amdgcn_mfma_f32_16x16x32_bf16(ah[mi], xx[ni], acc[mi][ni], 0, 0, 0);
    }

    int nb = n0 >> 7;
    unsigned int* dst = (nb < 2) ? Qp : (nb < 4) ? Kp : Vp;
    int qrow = (ln >> 4) * 4;
#pragma unroll
    for (int ni = 0; ni < 4; ++ni) {
        int col = (n0 & 255) + ncol + ni * 16 + fm;
        float bias = bqkv[n0 + ncol + ni * 16 + fm];
#pragma unroll
        for (int mi = 0; mi < 4; ++mi) {
#pragma unroll
            for (int r = 0; r < 4; ++r) {
                int m = m0 + mrow + mi * 16 + qrow + r;
                dst[(size_t)m * 256 + col] = pack2(acc[mi][ni][r] + bias);
            }
        }
    }
}

// ---------------------------------------------------------------------------
// K1b: transpose Vp -> Vtp[win][c][64] packed, pads zeroed. grid 512.
__global__ __launch_bounds__(256) void k_transpose_v(
    const unsigned int* __restrict__ Vp, unsigned int* __restrict__ Vtp) {
    __shared__ unsigned int T[49][257];
    int win = blockIdx.x;
    int tid = threadIdx.x;
#pragma unroll 1
    for (int i = tid; i < 49 * 64; i += 256) {
        int tok = i >> 6, cq = (i & 63) * 4;
        uint4 v = *(const uint4*)&Vp[((size_t)win * 49 + tok) * 256 + cq];
        T[tok][cq + 0] = v.x;
        T[tok][cq + 1] = v.y;
        T[tok][cq + 2] = v.z;
        T[tok][cq + 3] = v.w;
    }
    __syncthreads();
#pragma unroll 1
    for (int it = 0; it < 8; ++it) {
        int item = tid + it * 256;
        int c = item >> 3, t8 = (item & 7) * 8;
        uint4 o0, o1;
        o0.x = (t8 + 0 < 49) ? T[t8 + 0][c] : 0u;
        o0.y = (t8 + 1 < 49) ? T[t8 + 1][c] : 0u;
        o0.z = (t8 + 2 < 49) ? T[t8 + 2][c] : 0u;
        o0.w = (t8 + 3 < 49) ? T[t8 + 3][c] : 0u;
        o1.x = (t8 + 4 < 49) ? T[t8 + 4][c] : 0u;
        o1.y = (t8 + 5 < 49) ? T[t8 + 5][c] : 0u;
        o1.z = (t8 + 6 < 49) ? T[t8 + 6][c] : 0u;
        o1.w = (t8 + 7 < 49) ? T[t8 + 7][c] : 0u;
        size_t o = (size_t)win * 16384 + (size_t)c * 64 + t8;
        *(uint4*)&Vtp[o] = o0;
        *(uint4*)&Vtp[o + 4] = o1;
    }
}

// ---------------------------------------------------------------------------
// K2a: QK^T + softmax + packed P store, w-SPLIT. grid 1024, block 256.
// blk: batch=blk&7 (XCD), idx=blk>>3, win=batch*64+(idx>>1), wh=idx&1.
// Block handles w rows [wh*32, wh*32+32). wave = region.
__global__ __launch_bounds__(256) void k_attn_logits2(
    const unsigned int* __restrict__ Qp, const unsigned int* __restrict__ Kp,
    const int* __restrict__ topk, const float* __restrict__ gwt,
    unsigned int* __restrict__ Pp) {
    __shared__ float redm[4][32];
    __shared__ float reds[4][32];
    __shared__ float gmax[32];
    __shared__ float ginv[32];
    int blk = blockIdx.x;
    int batch = blk & 7, idx = blk >> 3;
    int win = (batch << 6) | (idx >> 1);
    int wh = idx & 1;
    int b = batch;
    int tid = threadIdx.x, ln = tid & 63, wv = tid >> 6;
    int fm = ln & 15, g = ln >> 4, fq = g * 8;

    int myreg = topk[win * 4 + wv];
    float gw = gwt[win * 4 + wv];
    float sg = SCALE * gw;
    size_t qbase = (size_t)win * 49 * 256;
    size_t kbase = (size_t)(b * 64 + myreg) * 49 * 256;

    // A-fragment rows (clamped >=49 -> 48; masked later)
    int arow[2];
#pragma unroll
    for (int mi = 0; mi < 2; ++mi) {
        int w = wh * 32 + mi * 16 + fm;
        arow[mi] = (w < 49) ? w : 48;
    }

    f32x4 acc[2][4];
#pragma unroll
    for (int i = 0; i < 2; ++i)
#pragma unroll
        for (int j = 0; j < 4; ++j) acc[i][j] = (f32x4){0.f, 0.f, 0.f, 0.f};

#pragma unroll 1
    for (int kc = 0; kc < 256; kc += 32) {
        short8 ah[2], al[2], bh[4], bl[4];
#pragma unroll
        for (int mi = 0; mi < 2; ++mi)
            load_unpack8(&Qp[qbase + (size_t)arow[mi] * 256 + kc + fq], ah[mi], al[mi]);
#pragma unroll
        for (int ni = 0; ni < 4; ++ni) {
            int tok = ni * 16 + fm;
            int trow = (tok < 49) ? tok : 48;
            load_unpack8(&Kp[kbase + (size_t)trow * 256 + kc + fq], bh[ni], bl[ni]);
        }
#pragma unroll
        for (int mi = 0; mi < 2; ++mi)
#pragma unroll
            for (int ni = 0; ni < 4; ++ni) {
                acc[mi][ni] = __builtin_amdgcn_mfma_f32_16x16x32_bf16(ah[mi], bh[ni], acc[mi][ni], 0, 0, 0);
                acc[mi][ni] = __builtin_amdgcn_mfma_f32_16x16x32_bf16(al[mi], bh[ni], acc[mi][ni], 0, 0, 0);
                acc[mi][ni] = __builtin_amdgcn_mfma_f32_16x16x32_bf16(ah[mi], bl[ni], acc[mi][ni], 0, 0, 0);
            }
    }

#pragma unroll
    for (int mi = 0; mi < 2; ++mi)
#pragma unroll
        for (int ni = 0; ni < 4; ++ni) acc[mi][ni] *= sg;

    float rmax[2][4];
#pragma unroll
    for (int mi = 0; mi < 2; ++mi)
#pragma unroll
        for (int r = 0; r < 4; ++r) rmax[mi][r] = -3.0e38f;
#pragma unroll
    for (int mi = 0; mi < 2; ++mi)
#pragma unroll
        for (int ni = 0; ni < 4; ++ni) {
            if (ni * 16 + fm < 49) {
#pragma unroll
                for (int r = 0; r < 4; ++r)
                    rmax[mi][r] = fmaxf(rmax[mi][r], acc[mi][ni][r]);
            }
        }
#pragma unroll
    for (int off = 1; off < 16; off <<= 1)
#pragma unroll
        for (int mi = 0; mi < 2; ++mi)
#pragma unroll
            for (int r = 0; r < 4; ++r)
                rmax[mi][r] = fmaxf(rmax[mi][r], __shfl_xor(rmax[mi][r], off, 64));
    if (fm == 0) {
#pragma unroll
        for (int mi = 0; mi < 2; ++mi)
#pragma unroll
            for (int r = 0; r < 4; ++r)
                redm[wv][mi * 16 + g * 4 + r] = rmax[mi][r];
    }
    __syncthreads();
    if (tid < 32)
        gmax[tid] = fmaxf(fmaxf(redm[0][tid], redm[1][tid]),
                          fmaxf(redm[2][tid], redm[3][tid]));
    __syncthreads();

    float gm[2][4];
#pragma unroll
    for (int mi = 0; mi < 2; ++mi)
#pragma unroll
        for (int r = 0; r < 4; ++r) gm[mi][r] = gmax[mi * 16 + g * 4 + r];
    float rsum[2][4];
#pragma unroll
    for (int mi = 0; mi < 2; ++mi)
#pragma unroll
        for (int r = 0; r < 4; ++r) rsum[mi][r] = 0.f;
#pragma unroll
    for (int mi = 0; mi < 2; ++mi)
#pragma unroll
        for (int ni = 0; ni < 4; ++ni) {
            bool valid = (ni * 16 + fm) < 49;
#pragma unroll
            for (int r = 0; r < 4; ++r) {
                float e = valid ? __expf(acc[mi][ni][r] - gm[mi][r]) : 0.f;
                acc[mi][ni][r] = e;
                rsum[mi][r] += e;
            }
        }
#pragma unroll
    for (int off = 1; off < 16; off <<= 1)
#pragma unroll
        for (int mi = 0; mi < 2; ++mi)
#pragma unroll
            for (int r = 0; r < 4; ++r)
                rsum[mi][r] += __shfl_xor(rsum[mi][r], off, 64);
    if (fm == 0) {
#pragma unroll
        for (int mi = 0; mi < 2; ++mi)
#pragma unroll
            for (int r = 0; r < 4; ++r)
                reds[wv][mi * 16 + g * 4 + r] = rsum[mi][r];
    }
    __syncthreads();
    if (tid < 32)
        ginv[tid] = 1.0f / (reds[0][tid] + reds[1][tid] + reds[2][tid] + reds[3][tid]);
    __syncthreads();

    // packed P store (4B/lane, 64B segments); rows >=49 get zeros
    size_t pbase = (size_t)win * 16384 + wv * 64;
#pragma unroll
    for (int mi = 0; mi < 2; ++mi) {
#pragma unroll
        for (int r = 0; r < 4; ++r) {
            int rowb = mi * 16 + g * 4 + r;
            int w = wh * 32 + rowb;
            float giv = (w < 49) ? ginv[rowb] * gw : 0.f;
#pragma unroll
            for (int ni = 0; ni < 4; ++ni) {
                float p = acc[mi][ni][r] * giv;
                Pp[pbase + (size_t)w * 256 + ni * 16 + fm] = pack2(p);
            }
        }
    }
}

// ---------------------------------------------------------------------------
// K2b: PV + fused dwconv, w-SPLIT. grid 1024, block 256 (wave = 64-col strip).
// LDS stages only the tok-ring needed by this half's dwconv.
__global__ __launch_bounds__(256) void k_attn_pv2(
    const unsigned int* __restrict__ Pp, const unsigned int* __restrict__ Vtp,
    const unsigned int* __restrict__ Vp,
    const int* __restrict__ topk, const float* __restrict__ dwk,
    const float* __restrict__ dwb, unsigned int* __restrict__ ATTp) {
    __shared__ unsigned int Vs[42][258];  // staged tok-ring, tok-major, padded
    int blk = blockIdx.x;
    int batch = blk & 7, idx = blk >> 3;
    int win = (batch << 6) | (idx >> 1);
    int wh = idx & 1;
    int b = batch;
    int tid = threadIdx.x, ln = tid & 63, wv = tid >> 6;
    int fm = ln & 15, g = ln >> 4, fq = g * 8;
    int ncol = wv * 64;
    size_t pbase = (size_t)win * 16384;

    // stage tok ring: half 0 -> toks 0..41, half 1 -> toks 21..48
    int lo = wh ? 21 : 0;
    int cnt = wh ? 28 : 42;
#pragma unroll 1
    for (int i = tid; i < cnt * 64; i += 256) {
        int tok = lo + (i >> 6), cq = (i & 63) * 4;
        uint4 v = *(const uint4*)&Vp[((size_t)win * 49 + tok) * 256 + cq];
        Vs[tok - lo][cq + 0] = v.x;
        Vs[tok - lo][cq + 1] = v.y;
        Vs[tok - lo][cq + 2] = v.z;
        Vs[tok - lo][cq + 3] = v.w;
    }
    __syncthreads();

    f32x4 oacc[2][4];
#pragma unroll
    for (int i = 0; i < 2; ++i)
#pragma unroll
        for (int j = 0; j < 4; ++j) oacc[i][j] = (f32x4){0.f, 0.f, 0.f, 0.f};

#pragma unroll 1
    for (int r = 0; r < 4; ++r) {
        int reg = topk[win * 4 + r];
        size_t vbase = (size_t)(b * 64 + reg) * 16384;
#pragma unroll
        for (int half = 0; half < 2; ++half) {
            int kc = r * 64 + half * 32;
            int tokoff = half * 32;
            short8 ah[2], al[2], bh[4], bl[4];
#pragma unroll
            for (int mi = 0; mi < 2; ++mi)
                load_unpack8(&Pp[pbase + (size_t)(wh * 32 + mi * 16 + fm) * 256 + kc + fq], ah[mi], al[mi]);
#pragma unroll
            for (int ni = 0; ni < 4; ++ni)
                load_unpack8(&Vtp[vbase + (size_t)(ncol + ni * 16 + fm) * 64 + tokoff + fq], bh[ni], bl[ni]);
#pragma unroll
            for (int mi = 0; mi < 2; ++mi)
#pragma unroll
                for (int ni = 0; ni < 4; ++ni) {
                    oacc[mi][ni] = __builtin_amdgcn_mfma_f32_16x16x32_bf16(ah[mi], bh[ni], oacc[mi][ni], 0, 0, 0);
                    oacc[mi][ni] = __builtin_amdgcn_mfma_f32_16x16x32_bf16(al[mi], bh[ni], oacc[mi][ni], 0, 0, 0);
                    oacc[mi][ni] = __builtin_amdgcn_mfma_f32_16x16x32_bf16(ah[mi], bl[ni], oacc[mi][ni], 0, 0, 0);
                }
        }
    }

    // epilogue: dwconv from LDS ring + packed store
#pragma unroll 1
    for (int ni = 0; ni < 4; ++ni) {
        int c = ncol + ni * 16 + fm;
        float dk[9];
#pragma unroll
        for (int t = 0; t < 9; ++t) dk[t] = dwk[(size_t)t * 256 + c];
        float db = dwb[c];
#pragma unroll
        for (int mi = 0; mi < 2; ++mi) {
#pragma unroll
            for (int rr = 0; rr < 4; ++rr) {
                int w = wh * 32 + mi * 16 + g * 4 + rr;
                if (w < 49) {
                    int py = w / 7, px = w - py * 7;
                    float vd = db;
#pragma unroll
                    for (int dy = 0; dy < 3; ++dy) {
                        int yy = py + dy - 1;
                        if (yy < 0 || yy > 6) continue;
#pragma unroll
                        for (int dx = 0; dx < 3; ++dx) {
                            int xx = px + dx - 1;
                            if (xx < 0 || xx > 6) continue;
                            vd += unpack_f(Vs[yy * 7 + xx - lo][c]) * dk[dy * 3 + dx];
                        }
                    }
                    ATTp[((size_t)win * 49 + w) * 256 + c] = pack2(oacc[mi][ni][rr] + vd);
                }
            }
        }
    }
}

// ---------------------------------------------------------------------------
// K3: proj GEMM, split-bf16 MFMA. A = packed ATT staged into padded LDS.
__global__ __launch_bounds__(256) void k_mm_proj(
    const unsigned int* __restrict__ Ap,
    const unsigned short* __restrict__ whi, const unsigned short* __restrict__ wlo,
    const float* __restrict__ bp, float* __restrict__ out) {
    __shared__ __align__(16) unsigned int As[128 * 36];
    __shared__ __align__(16) unsigned short Bh[4096];
    __shared__ __align__(16) unsigned short Bl[4096];
    int tid = threadIdx.x;
    int ln = tid & 63, wv = tid >> 6;
    int m0 = blockIdx.y * 128, n0 = blockIdx.x * 128;
    int mrow = (wv >> 1) * 64, ncol = (wv & 1) * 64;

    int lrow = ln >> 2, lseg = (ln & 3) * 8;
    const unsigned short* gB0 = whi + (size_t)(n0 + wv * 32 + lrow) * 256 + lseg;
    const unsigned short* gB1 = gB0 + 16 * 256;
    const unsigned short* gBl0 = wlo + (size_t)(n0 + wv * 32 + lrow) * 256 + lseg;
    const unsigned short* gBl1 = gBl0 + 16 * 256;
    unsigned short* lB0 = &Bh[(wv * 32) * 32];
    unsigned short* lB1 = &Bh[(wv * 32 + 16) * 32];
    unsigned short* lBl0 = &Bl[(wv * 32) * 32];
    unsigned short* lBl1 = &Bl[(wv * 32 + 16) * 32];

    int arow = ln >> 3, akk = (ln & 7) * 4;
    int fm = ln & 15, fq = (ln >> 4) * 8;
    f32x4 acc[4][4];
#pragma unroll
    for (int i = 0; i < 4; ++i)
#pragma unroll
        for (int j = 0; j < 4; ++j) acc[i][j] = (f32x4){0.f, 0.f, 0.f, 0.f};

#pragma unroll 1
    for (int kc = 0; kc < 8; ++kc) {
        if (kc) __syncthreads();
        gload16(gB0, lB0); gload16(gB1, lB1);
        gload16(gBl0, lBl0); gload16(gBl1, lBl1);
        gB0 += 32; gB1 += 32; gBl0 += 32; gBl1 += 32;
#pragma unroll
        for (int it = 0; it < 4; ++it) {
            int row = wv * 32 + it * 8 + arow;
            uint4 v = *(const uint4*)&Ap[(size_t)(m0 + row) * 256 + kc * 32 + akk];
            *(uint4*)&As[row * 36 + akk] = v;
        }
        __syncthreads();

        short8 ah[4], al[4], bh[4], xx[4];
#pragma unroll
        for (int mi = 0; mi < 4; ++mi) {
            const unsigned int* p = &As[(mrow + mi * 16 + fm) * 36 + fq];
            unpack_u4(*(const uint4*)p, *(const uint4*)(p + 4), ah[mi], al[mi]);
        }
#pragma unroll
        for (int ni = 0; ni < 4; ++ni)
            bh[ni] = *(const short8*)&Bh[(ncol + ni * 16 + fm) * 32 + fq];
#pragma unroll
        for (int mi = 0; mi < 4; ++mi)
#pragma unroll
            for (int ni = 0; ni < 4; ++ni)
                acc[mi][ni] = __builtin_amdgcn_mfma_f32_16x16x32_bf16(ah[mi], bh[ni], acc[mi][ni], 0, 0, 0);
#pragma unroll
        for (int mi = 0; mi < 4; ++mi)
#pragma unroll
            for (int ni = 0; ni < 4; ++ni)
                acc[mi][ni] = __builtin_amdgcn_mfma_f32_16x16x32_bf16(al[mi], bh[ni], acc[mi][ni], 0, 0, 0);
#pragma unroll
        for (int ni = 0; ni < 4; ++ni)
            xx[ni] = *(const short8*)&Bl[(ncol + ni * 16 + fm) * 32 + fq];
#pragma unroll
        for (int mi = 0; mi < 4; ++mi)
#pragma unroll
            for (int ni = 0; ni < 4; ++ni)
                acc[mi][ni] = __builtin_amdgcn_mfma_f32_16x16x32_bf16(ah[mi], xx[ni], acc[mi][ni], 0, 0, 0);
    }

    int qrow = (ln >> 4) * 4;
#pragma unroll
    for (int mi = 0; mi < 4; ++mi) {
#pragma unroll
        for (int r = 0; r < 4; ++r) {
            int m = m0 + mrow + mi * 16 + qrow + r;
            size_t orow = (size_t)token_row_addr(m);
#pragma unroll
            for (int ni = 0; ni < 4; ++ni) {
                int col = n0 + ncol + ni * 16 + fm;
                out[orow * 256 + col] = acc[mi][ni][r] + bp[col];
            }
        }
    }
}

// ---------------------------------------------------------------------------
extern "C" void kernel_launch(void* const* d_in, const int* in_sizes, int n_in,
                              void* d_out, int out_size, void* d_ws, size_t ws_size,
                              hipStream_t stream) {
    const float* x    = (const float*)d_in[0];
    const float* wqkv = (const float*)d_in[1];
    const float* bqkv = (const float*)d_in[2];
    const float* wg1  = (const float*)d_in[3];
    const float* bg1  = (const float*)d_in[4];
    const float* wg2  = (const float*)d_in[5];
    const float* bg2  = (const float*)d_in[6];
    const float* dwk  = (const float*)d_in[7];
    const float* dwb  = (const float*)d_in[8];
    const float* wp   = (const float*)d_in[9];
    const float* bp   = (const float*)d_in[10];
    float* out = (float*)d_out;

    const size_t NTOT = (size_t)25088 * 256;     // 6,422,528
    const size_t VTSZ = (size_t)512 * 256 * 64;  // 8,388,608
    unsigned int* Qp  = (unsigned int*)d_ws;
    unsigned int* Kp  = Qp + NTOT;
    unsigned int* Vp  = Kp + NTOT;
    unsigned int* Vtp = Vp + NTOT;
    unsigned int* Pp  = Vtp + VTSZ;
    unsigned short* XH = (unsigned short*)(Pp + VTSZ);  // x bf16 hi; later ATTp
    unsigned short* XL = XH + NTOT;                     // x bf16 lo
    unsigned int* ATTp = (unsigned int*)XH;             // alias (x dead after qkv)
    unsigned short* WQH = XL + NTOT;
    unsigned short* WQL = WQH + 768 * 256;
    unsigned short* WPH = WQL + 768 * 256;
    unsigned short* WPL = WPH + 256 * 256;
    float* QKVR = (float*)(WPL + 256 * 256);
    float* SIG  = QKVR + 512 * 768;
    float* GWT  = SIG + 1024;
    int*   TOPK = (int*)(GWT + 2048);

    hipLaunchKernelGGL(k_cvt_x, dim3(25088), dim3(256), 0, stream, x, XH, XL);
    hipLaunchKernelGGL(k_cvt_w, dim3(768), dim3(256), 0, stream, wqkv, 768, WQH, WQL);
    hipLaunchKernelGGL(k_cvt_w, dim3(256), dim3(256), 0, stream, wp, 256, WPH, WPL);
    hipLaunchKernelGGL(k_region_fused, dim3(512), dim3(256), 0, stream,
                       x, wqkv, bqkv, wg1, bg1, wg2, bg2, QKVR, SIG);
    hipLaunchKernelGGL(k_topk_gauss, dim3(512), dim3(64), 0, stream, QKVR, SIG, TOPK, GWT);
    hipLaunchKernelGGL(k_mm_qkv, dim3(6, 196), dim3(256), 0, stream,
                       XH, XL, WQH, WQL, bqkv, Qp, Kp, Vp);
    hipLaunchKernelGGL(k_transpose_v, dim3(512), dim3(256), 0, stream, Vp, Vtp);
    hipLaunchKernelGGL(k_attn_logits2, dim3(1024), dim3(256), 0, stream,
                       Qp, Kp, TOPK, GWT, Pp);
    hipLaunchKernelGGL(k_attn_pv2, dim3(1024), dim3(256), 0, stream,
                       Pp, Vtp, Vp, TOPK, dwk, dwb, ATTp);
    hipLaunchKernelGGL(k_mm_proj, dim3(2, 196), dim3(256), 0, stream,
                       ATTp, WPH, WPL, bp, out);
}